// Round 32
// baseline (186.845 us; speedup 1.0000x reference)
//
#include <hip/hip_runtime.h>
#include <hip/hip_bf16.h>
#include <cstdint>

// Problem constants
#define BB 2
#define SS 2048
#define DD 768
#define HH 12
#define DHH 64
#define DFF 3072
#define MM (BB * SS)   // 4096

typedef __attribute__((ext_vector_type(8))) short bf16x8;
typedef __attribute__((ext_vector_type(4))) float f32x4;
typedef __attribute__((ext_vector_type(16))) float f32x16;
typedef __attribute__((ext_vector_type(4))) unsigned short u16x4;
typedef __attribute__((ext_vector_type(8))) unsigned short u16x8;
typedef unsigned int u32;

#define DEV static __device__ __forceinline__

typedef __attribute__((address_space(1))) void AS1void;
typedef __attribute__((address_space(3))) void AS3void;

DEV void async_copy16(const void* g, void* l) {
  __builtin_amdgcn_global_load_lds((AS1void*)g, (AS3void*)l, 16, 0, 0);
}

DEV unsigned short bf16bits(float f) {
  __hip_bfloat16 h = __float2bfloat16(f);
  return *(unsigned short*)&h;
}

DEV float bits2f(unsigned short u) {
  u32 x = ((u32)u) << 16;
  union { u32 u; float f; } c; c.u = x;
  return c.f;
}

DEV u32 pack2(float a, float b) {
  return ((u32)bf16bits(b) << 16) | (u32)bf16bits(a);
}

// ---------------- Fused prolog: qkv-transpose + W-transposes + LN1 ----------------
__global__ __launch_bounds__(256) void prolog_kernel(
    const float* __restrict__ Wq, const float* __restrict__ Wk,
    const float* __restrict__ Wv, const float* __restrict__ bq,
    const float* __restrict__ bk, const float* __restrict__ bv,
    __hip_bfloat16* __restrict__ WqkvT, float* __restrict__ qkvbias,
    const float* __restrict__ W0, const float* __restrict__ W1,
    const float* __restrict__ W2, __hip_bfloat16* __restrict__ W0T,
    __hip_bfloat16* __restrict__ W1T, __hip_bfloat16* __restrict__ W2T,
    const float* __restrict__ X, const float* __restrict__ g1,
    const float* __restrict__ o1, __hip_bfloat16* __restrict__ ln1)
{
  __shared__ float tile[64][65];
  const int bid = blockIdx.x;

  if (bid < 432) {
    const int y = bid % 12, z = bid / 12;
    const int p = z / HH, h = z - p * HH;
    const float* in = (p == 0 ? Wq : (p == 1 ? Wk : Wv)) + (size_t)h * DD * DHH;
    const int r0 = y * 64;
    if (y == 0 && threadIdx.x < DHH) {
      const float* bsrc = (p == 0 ? bq : (p == 1 ? bk : bv));
      qkvbias[p * DD + h * DHH + threadIdx.x] = bsrc[h * DHH + threadIdx.x];
    }
    for (int i = threadIdx.x; i < 4096; i += 256) {
      int r = i >> 6, c = i & 63;
      tile[r][c] = in[(size_t)(r0 + r) * DHH + c];
    }
    __syncthreads();
    for (int i = threadIdx.x; i < 4096; i += 256) {
      int c = i >> 6, r = i & 63;
      WqkvT[(size_t)(p * DD + h * DHH + c) * DD + r0 + r] = __float2bfloat16(tile[r][c]);
    }
  } else if (bid < 1728) {
    int id = bid - 432;
    const float* in; __hip_bfloat16* out; int R, C, xt, yt;
    if (id < 144)      { in = W0; out = W0T; R = DD;  C = DD;  xt = id % 12; yt = id / 12; }
    else if (id < 720) { id -= 144; in = W1; out = W1T; R = DD;  C = DFF; xt = id % 48; yt = id / 48; }
    else               { id -= 720; in = W2; out = W2T; R = DFF; C = DD;  xt = id % 12; yt = id / 12; }
    const int c0 = xt * 64, r0 = yt * 64;
    for (int i = threadIdx.x; i < 4096; i += 256) {
      int r = i >> 6, c = i & 63;
      tile[r][c] = in[(size_t)(r0 + r) * C + c0 + c];
    }
    __syncthreads();
    for (int i = threadIdx.x; i < 4096; i += 256) {
      int c = i >> 6, r = i & 63;
      out[(size_t)(c0 + c) * R + r0 + r] = __float2bfloat16(tile[r][c]);
    }
  } else {
    const int wave = threadIdx.x >> 6;
    const int lane = threadIdx.x & 63;
    const int row = (bid - 1728) * 4 + wave;
    const float* xr = X + (size_t)row * DD;

    float4 v[3];
    float s1 = 0.f, s2 = 0.f;
#pragma unroll
    for (int j = 0; j < 3; ++j) {
      v[j] = *(const float4*)(xr + (j * 64 + lane) * 4);
      s1 += v[j].x + v[j].y + v[j].z + v[j].w;
      s2 += v[j].x * v[j].x + v[j].y * v[j].y + v[j].z * v[j].z + v[j].w * v[j].w;
    }
#pragma unroll
    for (int d = 1; d < 64; d <<= 1) {
      s1 += __shfl_xor(s1, d);
      s2 += __shfl_xor(s2, d);
    }
    const float mean = s1 * (1.0f / 768.0f);
    const float var = fmaxf(s2 * (1.0f / 768.0f) - mean * mean, 0.0f);
    const float rs = 1.0f / (sqrtf(var) + 1e-5f);

    unsigned short* orow = (unsigned short*)ln1 + (size_t)row * DD;
#pragma unroll
    for (int j = 0; j < 3; ++j) {
      const int c = (j * 64 + lane) * 4;
      float4 g4 = *(const float4*)(g1 + c);
      float4 o4 = *(const float4*)(o1 + c);
      u16x4 pk;
      pk[0] = bf16bits(g4.x * ((v[j].x - mean) * rs) + o4.x);
      pk[1] = bf16bits(g4.y * ((v[j].y - mean) * rs) + o4.y);
      pk[2] = bf16bits(g4.z * ((v[j].z - mean) * rs) + o4.z);
      pk[3] = bf16bits(g4.w * ((v[j].w - mean) * rs) + o4.w);
      *(u16x4*)(orow + c) = pk;
    }
  }
}

// ---------------- QKV GEMM with LDS-staged K/V fragment-image epilogue ----------------
// A=ln1 [4096][768], BT=WqkvT [2304][768]. Column blocks align with Q/K/V
// boundaries -> block-uniform branch:
//   bn <  768 : Q -> qbuf [4096][768] (compact)
//   else      : K/V -> fragment images. acc is staged per 64-row t-subtile
//               into a [64][136] bf16 LDS tile (reusing Alds/Blds, dead after
//               the K-loop), then the EXACT kvimg inner loop writes coalesced
//               16B image stores. Mapping verified on-HW in r30 (passed);
//               r30's failure was the scattered 2B stores, eliminated here.
__global__ __launch_bounds__(256) void gemm_qkv(
    const __hip_bfloat16* __restrict__ A, const __hip_bfloat16* __restrict__ BT,
    const float* __restrict__ bias, __hip_bfloat16* __restrict__ qbuf,
    char* __restrict__ kimg, char* __restrict__ vimg)
{
  const int K = DD;
  __shared__ __align__(16) char smem[32768];
  __hip_bfloat16* Alds = (__hip_bfloat16*)smem;             // [2][4096]
  __hip_bfloat16* Blds = (__hip_bfloat16*)(smem + 16384);   // [2][4096]
  const int tid = threadIdx.x;
  const int wave = tid >> 6;
  const int lane = tid & 63;
  const int fr = lane & 15, fq = lane >> 4;
  const int wr = wave >> 1, wc = wave & 1;
  const int bm = blockIdx.y * 128, bn = blockIdx.x * 128;

  const int srow = tid >> 2;
  const int scol = (tid & 3) * 8;
  const __hip_bfloat16* ag0 = A + (size_t)(bm + srow) * K + scol;
  const __hip_bfloat16* ag1 = A + (size_t)(bm + 64 + srow) * K + scol;
  const __hip_bfloat16* bg0 = BT + (size_t)(bn + srow) * K + scol;
  const __hip_bfloat16* bg1 = BT + (size_t)(bn + 64 + srow) * K + scol;
  const int so = wave * 512;

  f32x4 acc[4][4] = {};

  async_copy16(ag0, &Alds[so]);
  async_copy16(ag1, &Alds[2048 + so]);
  async_copy16(bg0, &Blds[so]);
  async_copy16(bg1, &Blds[2048 + so]);
  __syncthreads();

  const int niter = K / 32;
  for (int i = 0; i < niter; ++i) {
    const int cur = i & 1;
    if (i + 1 < niter) {
      const int k1 = (i + 1) * 32;
      async_copy16(ag0 + k1, &Alds[(cur ^ 1) * 4096 + so]);
      async_copy16(ag1 + k1, &Alds[(cur ^ 1) * 4096 + 2048 + so]);
      async_copy16(bg0 + k1, &Blds[(cur ^ 1) * 4096 + so]);
      async_copy16(bg1 + k1, &Blds[(cur ^ 1) * 4096 + 2048 + so]);
    }
    bf16x8 af[4], bfr[4];
#pragma unroll
    for (int i4 = 0; i4 < 4; ++i4)
      af[i4] = *(const bf16x8*)(&Alds[cur * 4096 + (wr * 64 + i4 * 16 + fr) * 32 + fq * 8]);
#pragma unroll
    for (int j4 = 0; j4 < 4; ++j4)
      bfr[j4] = *(const bf16x8*)(&Blds[cur * 4096 + (wc * 64 + j4 * 16 + fr) * 32 + fq * 8]);
#pragma unroll
    for (int i4 = 0; i4 < 4; ++i4)
#pragma unroll
      for (int j4 = 0; j4 < 4; ++j4)
        acc[i4][j4] = __builtin_amdgcn_mfma_f32_16x16x32_bf16(af[i4], bfr[j4], acc[i4][j4], 0, 0, 0);
    __syncthreads();
  }

  if (bn < DD) {
    // ---- Q: compact [4096][768] (same store pattern as the proven epilogue) ----
#pragma unroll
    for (int j = 0; j < 4; ++j) {
      const int c = bn + wc * 64 + j * 16 + fr;
      const float bv = bias[c];
#pragma unroll
      for (int i = 0; i < 4; ++i) {
#pragma unroll
        for (int r = 0; r < 4; ++r) {
          const int rr = bm + wr * 64 + i * 16 + fq * 4 + r;
          ((unsigned short*)qbuf)[(size_t)rr * DD + c] = bf16bits(acc[i][j][r] + bv);
        }
      }
    }
  } else {
    // ---- K/V: LDS-staged fragment-image build (kvimg loop, verbatim) ----
    const bool isV = (bn >= 2 * DD);
    const int hbase = (isV ? bn - 2 * DD : bn - DD) >> 6;  // head of col-half 0
    char* img = isV ? vimg : kimg;
    const int b = bm >> 11;               // uniform per block (2048 % 128 == 0)
    const int tbase = (bm >> 6) & 31;     // t-tile of row-half 0
    unsigned short (*tile)[136] = (unsigned short(*)[136])smem;  // 64x136x2 = 17408B

#pragma unroll
    for (int pass = 0; pass < 2; ++pass) {
      // stage rows [pass*64, pass*64+64): waves with wr==pass own them
      if (wr == pass) {
#pragma unroll
        for (int j = 0; j < 4; ++j) {
          const int c = wc * 64 + j * 16 + fr;        // 0..127 within tile
          const float bv = bias[bn + c];
#pragma unroll
          for (int i = 0; i < 4; ++i) {
#pragma unroll
            for (int r = 0; r < 4; ++r) {
              const int rloc = i * 16 + fq * 4 + r;   // 0..63
              tile[rloc][c] = bf16bits(acc[i][j][r] + bv);
            }
          }
        }
      }
      __syncthreads();
      const int t = tbase + pass;
#pragma unroll
      for (int hh = 0; hh < 2; ++hh) {
        char* dst = img + ((size_t)((b * HH + hbase + hh) * 32 + t)) * 8192;
        const int cb = hh * 64;
        for (int i = tid; i < 512; i += 256) {
          const int f = i >> 6, l = i & 63;
          const int kc = f >> 1, half = f & 1;
          const int lc = l & 31, lh = l >> 5;
          if (!isV) {
            *(bf16x8*)(dst + i * 16) =
                *(const bf16x8*)&tile[half * 32 + lc][cb + kc * 16 + lh * 8];
          } else {
            union { unsigned short u[8]; bf16x8 v; } w;
#pragma unroll
            for (int e = 0; e < 8; ++e)
              w.u[e] = tile[kc * 16 + lh * 8 + e][cb + half * 32 + lc];
            *(bf16x8*)(dst + i * 16) = w.v;
          }
        }
      }
      __syncthreads();
    }
  }
}

// ---------------- GEMM: bf16 A[M,K] x bf16 BT[N,K], 2-phase dbuf ----------------
template<bool RELU, bool OUT_BF16, bool HAS_RES>
__global__ __launch_bounds__(256) void gemm_bt(
    const __hip_bfloat16* __restrict__ A, const __hip_bfloat16* __restrict__ BT,
    const float* __restrict__ bias, const float* __restrict__ res,
    void* __restrict__ outp, int M, int N, int K)
{
  __shared__ __hip_bfloat16 Alds[2][128 * 32];
  __shared__ __hip_bfloat16 Blds[2][128 * 32];
  const int tid = threadIdx.x;
  const int wave = tid >> 6;
  const int lane = tid & 63;
  const int fr = lane & 15, fq = lane >> 4;
  const int wr = wave >> 1, wc = wave & 1;
  const int bm = blockIdx.y * 128, bn = blockIdx.x * 128;

  const int srow = tid >> 2;
  const int scol = (tid & 3) * 8;
  const __hip_bfloat16* ag0 = A + (size_t)(bm + srow) * K + scol;
  const __hip_bfloat16* ag1 = A + (size_t)(bm + 64 + srow) * K + scol;
  const __hip_bfloat16* bg0 = BT + (size_t)(bn + srow) * K + scol;
  const __hip_bfloat16* bg1 = BT + (size_t)(bn + 64 + srow) * K + scol;
  const int so = wave * 512;

  f32x4 acc[4][4] = {};

  async_copy16(ag0, &Alds[0][so]);
  async_copy16(ag1, &Alds[0][2048 + so]);
  async_copy16(bg0, &Blds[0][so]);
  async_copy16(bg1, &Blds[0][2048 + so]);
  __syncthreads();

  const int niter = K / 32;
  for (int i = 0; i < niter; ++i) {
    const int cur = i & 1;
    if (i + 1 < niter) {
      const int k1 = (i + 1) * 32;
      async_copy16(ag0 + k1, &Alds[cur ^ 1][so]);
      async_copy16(ag1 + k1, &Alds[cur ^ 1][2048 + so]);
      async_copy16(bg0 + k1, &Blds[cur ^ 1][so]);
      async_copy16(bg1 + k1, &Blds[cur ^ 1][2048 + so]);
    }
    bf16x8 af[4], bfr[4];
#pragma unroll
    for (int i4 = 0; i4 < 4; ++i4)
      af[i4] = *(const bf16x8*)(&Alds[cur][(wr * 64 + i4 * 16 + fr) * 32 + fq * 8]);
#pragma unroll
    for (int j4 = 0; j4 < 4; ++j4)
      bfr[j4] = *(const bf16x8*)(&Blds[cur][(wc * 64 + j4 * 16 + fr) * 32 + fq * 8]);
#pragma unroll
    for (int i4 = 0; i4 < 4; ++i4)
#pragma unroll
      for (int j4 = 0; j4 < 4; ++j4)
        acc[i4][j4] = __builtin_amdgcn_mfma_f32_16x16x32_bf16(af[i4], bfr[j4], acc[i4][j4], 0, 0, 0);
    __syncthreads();
  }

#pragma unroll
  for (int j = 0; j < 4; ++j) {
    const int c = bn + wc * 64 + j * 16 + fr;
    const float bv = bias[c];
#pragma unroll
    for (int i = 0; i < 4; ++i) {
#pragma unroll
      for (int r = 0; r < 4; ++r) {
        const int rr = bm + wr * 64 + i * 16 + fq * 4 + r;
        float v = acc[i][j][r] + bv;
        if (RELU) v = fmaxf(v, 0.0f);
        if (HAS_RES) v += res[(size_t)rr * N + c];
        if (OUT_BF16) ((__hip_bfloat16*)outp)[(size_t)rr * N + c] = __float2bfloat16(v);
        else          ((float*)outp)[(size_t)rr * N + c] = v;
      }
    }
  }
}

// ---------------- Split-K GEMM partial (2-phase dbuf): BF16 partial ----------------
// z < 2 -> part01 planes {0,1}; z >= 2 -> part23 planes {0,1}
__global__ __launch_bounds__(256) void gemm_bt_sk(
    const __hip_bfloat16* __restrict__ A, const __hip_bfloat16* __restrict__ BT,
    unsigned short* __restrict__ part01, unsigned short* __restrict__ part23,
    int M, int N, int K, int K_per)
{
  __shared__ __hip_bfloat16 Alds[2][128 * 32];
  __shared__ __hip_bfloat16 Blds[2][128 * 32];
  const int tid = threadIdx.x;
  const int wave = tid >> 6;
  const int lane = tid & 63;
  const int fr = lane & 15, fq = lane >> 4;
  const int wr = wave >> 1, wc = wave & 1;
  const int bm = blockIdx.y * 128, bn = blockIdx.x * 128;
  const int z = blockIdx.z;
  unsigned short* part = (z < 2 ? part01 : part23) + (size_t)(z & 1) * M * N;
  const int kbase = z * K_per;

  const int srow = tid >> 2;
  const int scol = (tid & 3) * 8;
  const __hip_bfloat16* ag0 = A + (size_t)(bm + srow) * K + scol + kbase;
  const __hip_bfloat16* ag1 = A + (size_t)(bm + 64 + srow) * K + scol + kbase;
  const __hip_bfloat16* bg0 = BT + (size_t)(bn + srow) * K + scol + kbase;
  const __hip_bfloat16* bg1 = BT + (size_t)(bn + 64 + srow) * K + scol + kbase;
  const int so = wave * 512;

  f32x4 acc[4][4] = {};

  async_copy16(ag0, &Alds[0][so]);
  async_copy16(ag1, &Alds[0][2048 + so]);
  async_copy16(bg0, &Blds[0][so]);
  async_copy16(bg1, &Blds[0][2048 + so]);
  __syncthreads();

  const int niter = K_per / 32;
  for (int i = 0; i < niter; ++i) {
    const int cur = i & 1;
    if (i + 1 < niter) {
      const int k1 = (i + 1) * 32;
      async_copy16(ag0 + k1, &Alds[cur ^ 1][so]);
      async_copy16(ag1 + k1, &Alds[cur ^ 1][2048 + so]);
      async_copy16(bg0 + k1, &Blds[cur ^ 1][so]);
      async_copy16(bg1 + k1, &Blds[cur ^ 1][2048 + so]);
    }
    bf16x8 af[4], bfr[4];
#pragma unroll
    for (int i4 = 0; i4 < 4; ++i4)
      af[i4] = *(const bf16x8*)(&Alds[cur][(wr * 64 + i4 * 16 + fr) * 32 + fq * 8]);
#pragma unroll
    for (int j4 = 0; j4 < 4; ++j4)
      bfr[j4] = *(const bf16x8*)(&Blds[cur][(wc * 64 + j4 * 16 + fr) * 32 + fq * 8]);
#pragma unroll
    for (int i4 = 0; i4 < 4; ++i4)
#pragma unroll
      for (int j4 = 0; j4 < 4; ++j4)
        acc[i4][j4] = __builtin_amdgcn_mfma_f32_16x16x32_bf16(af[i4], bfr[j4], acc[i4][j4], 0, 0, 0);
    __syncthreads();
  }

#pragma unroll
  for (int j = 0; j < 4; ++j) {
    const int c = bn + wc * 64 + j * 16 + fr;
#pragma unroll
    for (int i = 0; i < 4; ++i) {
#pragma unroll
      for (int r = 0; r < 4; ++r) {
        const int rr = bm + wr * 64 + i * 16 + fq * 4 + r;
        part[(size_t)rr * N + c] = bf16bits(acc[i][j][r]);
      }
    }
  }
}

// ---------------- combine 4 bf16 split-K partials + bias + residual -> fp32 ----------------
__global__ __launch_bounds__(256) void combine4(
    const unsigned short* __restrict__ part01, const unsigned short* __restrict__ part23,
    const float* __restrict__ res, const float* __restrict__ bias,
    float* __restrict__ out, int MN, int N)
{
  const int idx = (blockIdx.x * 256 + threadIdx.x) * 4;
  if (idx >= MN) return;
  const u16x4 a0 = *(const u16x4*)(part01 + idx);
  const u16x4 a1 = *(const u16x4*)(part01 + MN + idx);
  const u16x4 a2 = *(const u16x4*)(part23 + idx);
  const u16x4 a3 = *(const u16x4*)(part23 + MN + idx);
  const float4 rr = *(const float4*)(res + idx);
  const float4 bb = *(const float4*)(bias + (idx % N));
  float4 o;
  o.x = bits2f(a0[0]) + bits2f(a1[0]) + bits2f(a2[0]) + bits2f(a3[0]) + rr.x + bb.x;
  o.y = bits2f(a0[1]) + bits2f(a1[1]) + bits2f(a2[1]) + bits2f(a3[1]) + rr.y + bb.y;
  o.z = bits2f(a0[2]) + bits2f(a1[2]) + bits2f(a2[2]) + bits2f(a3[2]) + rr.z + bb.z;
  o.w = bits2f(a0[3]) + bits2f(a1[3]) + bits2f(a2[3]) + bits2f(a3[3]) + rr.w + bb.w;
  *(float4*)(out + idx) = o;
}

// ---------------- fused: combine 2 bf16 partials + bias + residual -> hbuf, then LN -> bf16 ----------------
__global__ __launch_bounds__(256) void combine2_ln(
    const unsigned short* __restrict__ part, const float* __restrict__ res,
    const float* __restrict__ bias, const float* __restrict__ gain,
    const float* __restrict__ off, float* __restrict__ hout,
    __hip_bfloat16* __restrict__ lnout)
{
  const int wave = threadIdx.x >> 6;
  const int lane = threadIdx.x & 63;
  const int row = blockIdx.x * 4 + wave;
  const int MN = MM * DD;
  const size_t rbase = (size_t)row * DD;

  float v[3][4];
  float s1 = 0.f, s2 = 0.f;
#pragma unroll
  for (int j = 0; j < 3; ++j) {
    const int c = (j * 64 + lane) * 4;
    const size_t idx = rbase + c;
    const u16x4 a0 = *(const u16x4*)(part + idx);
    const u16x4 a1 = *(const u16x4*)(part + MN + idx);
    const float4 rr = *(const float4*)(res + idx);
    const float4 bb = *(const float4*)(bias + c);
    v[j][0] = bits2f(a0[0]) + bits2f(a1[0]) + rr.x + bb.x;
    v[j][1] = bits2f(a0[1]) + bits2f(a1[1]) + rr.y + bb.y;
    v[j][2] = bits2f(a0[2]) + bits2f(a1[2]) + rr.z + bb.z;
    v[j][3] = bits2f(a0[3]) + bits2f(a1[3]) + rr.w + bb.w;
    float4 hv = { v[j][0], v[j][1], v[j][2], v[j][3] };
    *(float4*)(hout + idx) = hv;
    s1 += v[j][0] + v[j][1] + v[j][2] + v[j][3];
    s2 += v[j][0]*v[j][0] + v[j][1]*v[j][1] + v[j][2]*v[j][2] + v[j][3]*v[j][3];
  }
#pragma unroll
  for (int d = 1; d < 64; d <<= 1) {
    s1 += __shfl_xor(s1, d);
    s2 += __shfl_xor(s2, d);
  }
  const float mean = s1 * (1.0f / 768.0f);
  const float var = fmaxf(s2 * (1.0f / 768.0f) - mean * mean, 0.0f);
  const float rs = 1.0f / (sqrtf(var) + 1e-5f);

  unsigned short* orow = (unsigned short*)lnout + rbase;
#pragma unroll
  for (int j = 0; j < 3; ++j) {
    const int c = (j * 64 + lane) * 4;
    const float4 g4 = *(const float4*)(gain + c);
    const float4 o4 = *(const float4*)(off + c);
    u16x4 pk;
    pk[0] = bf16bits(g4.x * ((v[j][0] - mean) * rs) + o4.x);
    pk[1] = bf16bits(g4.y * ((v[j][1] - mean) * rs) + o4.y);
    pk[2] = bf16bits(g4.z * ((v[j][2] - mean) * rs) + o4.z);
    pk[3] = bf16bits(g4.w * ((v[j][3] - mean) * rs) + o4.w);
    *(u16x4*)(orow + c) = pk;
  }
}

// ---------------- Flash attention: register-fragment streams + K-prefetch (r18/r24) ----------------
// Q read from compact qbuf [4096][768] (verified r30).
__global__ __launch_bounds__(128, 3) void attn_kernel(
    const __hip_bfloat16* __restrict__ qbuf, const char* __restrict__ kimg,
    const char* __restrict__ vimg, __hip_bfloat16* __restrict__ outp)
{
  const int id = blockIdx.x;          // 0..1535
  const int xcd = id & 7;
  const int j = id >> 3;              // 0..191 within XCD
  const int s2 = 63 - j / 3;          // strip 0..63, heavy first
  const int bhl = j - 3 * (j / 3);
  const int bh = xcd * 3 + bhl;       // 24 heads = 8 XCD x 3
  const int b = bh / HH, h = bh - (bh / HH) * HH;

  const int q0w = s2 * 32;
  const int tid = threadIdx.x;
  const int c = tid >> 6;             // warp = kv-split index 0/1
  const int lane = tid & 63;
  const int col = lane & 31, hi = lane >> 5;
  const int qg = q0w + col;

  const __hip_bfloat16* Qp = qbuf + (size_t)b * SS * DD + h * DHH;
  const char* kimg_h = kimg + (size_t)bh * 32 * 8192;
  const char* vimg_h = vimg + (size_t)bh * 32 * 8192;

  __shared__ __align__(16) char sm[17408];

  bf16x8 qf[4];
#pragma unroll
  for (int kc = 0; kc < 4; ++kc)
    qf[kc] = *(const bf16x8*)(Qp + (size_t)qg * DD + kc * 16 + hi * 8);

  f32x16 o0 = {}, o1 = {};
  float mreg = -1e30f, lreg = 0.f;
  const float CS = 0.125f * 1.44269504f;   // (1/sqrt(64)) * log2(e)

  const int ntiles = (q0w >> 6) + 1;

  // prologue: K fragments of first tile
  bf16x8 kf[8];
  {
    const char* ks = kimg_h + (size_t)c * 8192 + lane * 16;
#pragma unroll
    for (int f = 0; f < 8; ++f) kf[f] = *(const bf16x8*)(ks + f * 1024);
  }

  for (int t = c; t < ntiles; t += 2) {
    const int kv0 = t * 64;
    // ---- QK^T (swapped): D col = q (lane-local) ----
    f32x16 s0 = {}, s1 = {};
    __builtin_amdgcn_s_setprio(1);
#pragma unroll
    for (int kc = 0; kc < 4; ++kc) {
      s0 = __builtin_amdgcn_mfma_f32_32x32x16_bf16(kf[kc * 2],     qf[kc], s0, 0, 0, 0);
      s1 = __builtin_amdgcn_mfma_f32_32x32x16_bf16(kf[kc * 2 + 1], qf[kc], s1, 0, 0, 0);
    }
    __builtin_amdgcn_s_setprio(0);
    // ---- issue V loads for this tile AND K loads for tile t+2 ----
    bf16x8 vf[8];
    {
      const char* vs = vimg_h + (size_t)t * 8192 + lane * 16;
#pragma unroll
      for (int f = 0; f < 8; ++f) vf[f] = *(const bf16x8*)(vs + f * 1024);
    }
    if (t + 2 < ntiles) {
      const char* ks = kimg_h + (size_t)(t + 2) * 8192 + lane * 16;
#pragma unroll
      for (int f = 0; f < 8; ++f) kf[f] = *(const bf16x8*)(ks + f * 1024);
    }
    // ---- causal mask (diagonal tile only) ----
    if (kv0 + 63 > q0w) {
#pragma unroll
      for (int r = 0; r < 16; ++r) {
        const int tl = (r & 3) + 8 * (r >> 2) + 4 * hi;
        s0[r] = (kv0 + tl <= qg) ? s0[r] : -1e30f;
        s1[r] = (kv0 + 32 + tl <= qg) ? s1[r] : -1e30f;
      }
    }
    // ---- online softmax, fully in-register ----
    float mx = s0[0];
#pragma unroll
    for (int r = 1; r < 16; ++r) mx = fmaxf(mx, s0[r]);
#pragma unroll
    for (int r = 0; r < 16; ++r) mx = fmaxf(mx, s1[r]);
    mx = fmaxf(mx, __shfl_xor(mx, 32));
    const float mnew = fmaxf(mreg, mx);
    const float alpha = exp2f((mreg - mnew) * CS);
    mreg = mnew;
    const float mc = mnew * CS;
    float ps = 0.f;
#pragma unroll
    for (int r = 0; r < 16; ++r) {
      const float p0 = exp2f(s0[r] * CS - mc); s0[r] = p0; ps += p0;
      const float p1 = exp2f(s1[r] * CS - mc); s1[r] = p1; ps += p1;
    }
    ps += __shfl_xor(ps, 32);
    lreg = lreg * alpha + ps;
#pragma unroll
    for (int r = 0; r < 16; ++r) { o0[r] *= alpha; o1[r] *= alpha; }

    // ---- pack P rows to bf16 pairs ----
    u32 pk0[4][2], pk1[4][2];
#pragma unroll
    for (int qd = 0; qd < 4; ++qd) {
      pk0[qd][0] = pack2(s0[4 * qd + 0], s0[4 * qd + 1]);
      pk0[qd][1] = pack2(s0[4 * qd + 2], s0[4 * qd + 3]);
      pk1[qd][0] = pack2(s1[4 * qd + 0], s1[4 * qd + 1]);
      pk1[qd][1] = pack2(s1[4 * qd + 2], s1[4 * qd + 3]);
    }
    // ---- PV: O += mfma(V-frag (A), P-frag (B)) ----
#pragma unroll
    for (int kc = 0; kc < 4; ++kc) {
      const int qa = 2 * (kc & 1), qb = qa + 1;
      const u32 A0 = (kc < 2) ? pk0[qa][0] : pk1[qa][0];
      const u32 A1 = (kc < 2) ? pk0[qa][1] : pk1[qa][1];
      const u32 B0 = (kc < 2) ? pk0[qb][0] : pk1[qb][0];
      const u32 B1 = (kc < 2) ? pk0[qb][1] : pk1[qb][1];
      const u32 send0 = hi ? A0 : B0;
      const u32 send1 = hi ? A1 : B1;
      const u32 recv0 = __shfl_xor(send0, 32);
      const u32 recv1 = __shfl_xor(send1, 32);
      const u32 su0 = hi ? B0 : A0;
      const u32 su1 = hi ? B1 : A1;
      union { u32 u[4]; bf16x8 v; } pf;
      pf.u[0] = hi ? recv0 : su0;
      pf.u[1] = hi ? recv1 : su1;
      pf.u[2] = hi ? su0 : recv0;
      pf.u[3] = hi ? su1 : recv1;
      __builtin_amdgcn_s_setprio(1);
      o0 = __builtin_amdgcn_mfma_f32_32x32x16_bf16(vf[kc * 2],     pf.v, o0, 0, 0, 0);
      o1 = __builtin_amdgcn_mfma_f32_32x32x16_bf16(vf[kc * 2 + 1], pf.v, o1, 0, 0, 0);
      __builtin_amdgcn_s_setprio(0);
    }
  }

  // ---- combine the 2 kv-split partials via LDS (1 barrier) ----
  float* opart = (float*)sm;                 // [2][32][65]
  float* mlp   = (float*)(sm + 16640);       // [c][0][q]=m, [c][1][q]=l
#pragma unroll
  for (int r = 0; r < 16; ++r) {
    const int d = (r & 3) + 8 * (r >> 2) + 4 * hi;
    opart[(c * 32 + col) * 65 + d]      = o0[r];
    opart[(c * 32 + col) * 65 + d + 32] = o1[r];
  }
  if (hi == 0) {
    mlp[c * 64 + col]      = mreg;
    mlp[c * 64 + 32 + col] = lreg;
  }
  __syncthreads();

  const int q = tid >> 2;            // 0..31
  const int d0 = (tid & 3) * 16;     // 0..48
  float mcv[2], lcv[2];
#pragma unroll
  for (int cc = 0; cc < 2; ++cc) {
    mcv[cc] = mlp[cc * 64 + q];
    lcv[cc] = mlp[cc * 64 + 32 + q];
  }
  const float mstar = fmaxf(mcv[0], mcv[1]);
  float av[2], lstar = 0.f;
#pragma unroll
  for (int cc = 0; cc < 2; ++cc) {
    av[cc] = exp2f((mcv[cc] - mstar) * CS);
    lstar += av[cc] * lcv[cc];
  }
  const float inv = 1.0f / lstar;
  float acc[16] = {};
#pragma unroll
  for (int cc = 0; cc < 2; ++cc) {
    const float a = av[cc];
#pragma unroll
    for (int e = 0; e < 16; ++e)
      acc[e] += a * opart[(cc * 32 + q) * 65 + d0 + e];
  }
  unsigned short* orow = (unsigned short*)outp +
      (size_t)(b * SS + q0w + q) * DD + h * DHH + d0;
  u16x8 w8;
#pragma unroll
  for (int e = 0; e < 8; ++e) w8[e] = bf16bits(acc[e] * inv);
  *(u16x8*)orow = w8;
#pragma unroll
  for (int e = 0; e < 8; ++e) w8[e] = bf16bits(acc[8 + e] * inv);
  *(u16x8*)(orow + 8) = w8;
}

// ---------------- host ----------------
extern "C" void kernel_launch(void* const* d_in, const int* in_sizes, int n_in,
                              void* d_out, int out_size, void* d_ws, size_t ws_size,
                              hipStream_t stream)
{
  (void)in_sizes; (void)n_in; (void)out_size; (void)ws_size;
  const float* X  = (const float*)d_in[0];
  const float* Wq = (const float*)d_in[1];
  const float* bq = (const float*)d_in[2];
  const float* Wk = (const float*)d_in[3];
  const float* bk = (const float*)d_in[4];
  const float* Wv = (const float*)d_in[5];
  const float* bv = (const float*)d_in[6];
  const float* W0 = (const float*)d_in[7];
  const float* b0 = (const float*)d_in[8];
  const float* W1 = (const float*)d_in[9];
  const float* b1 = (const float*)d_in[10];
  const float* W2 = (const float*)d_in[11];
  const float* b2 = (const float*)d_in[12];
  const float* g1 = (const float*)d_in[13];
  const float* o1 = (const float*)d_in[14];
  const float* g2 = (const float*)d_in[15];
  const float* o2 = (const float*)d_in[16];

  char* ws = (char*)d_ws;
  auto alloc = [&](size_t bytes) {
    char* p = ws;
    ws += (bytes + 255) & ~(size_t)255;
    return p;
  };
  __hip_bfloat16* ln1    = (__hip_bfloat16*)alloc((size_t)MM * DD * 2);
  __hip_bfloat16* qbuf   = (__hip_bfloat16*)alloc((size_t)MM * DD * 2);  // Q only
  __hip_bfloat16* attnb  = (__hip_bfloat16*)alloc((size_t)MM * DD * 2);
  float*          hbuf   = (float*)alloc((size_t)MM * DD * 4);
  __hip_bfloat16* ln2    = (__hip_bfloat16*)alloc((size_t)MM * DD * 2);
  __hip_bfloat16* ffn1   = (__hip_bfloat16*)alloc((size_t)MM * DFF * 2);
  __hip_bfloat16* WqkvT  = (__hip_bfloat16*)alloc((size_t)3 * DD * DD * 2);
  __hip_bfloat16* W0T    = (__hip_bfloat16*)alloc((size_t)DD * DD * 2);
  __hip_bfloat16* W1T    = (__hip_bfloat16*)alloc((size_t)DFF * DD * 2);
  __hip_bfloat16* W2T    = (__hip_bfloat16*)alloc((size_t)DD * DFF * 2);
  float*          qkvbias= (float*)alloc((size_t)3 * DD * 4);
  unsigned short* part23 = (unsigned short*)alloc((size_t)2 * MM * DD * 2);  // 2 bf16 planes
  char*           kimg   = alloc((size_t)24 * 32 * 8192);           // K fragment images
  char*           vimg   = alloc((size_t)24 * 32 * 8192);           // V fragment images
  // bf16 FFN2 splits 0,1 alias ln1+qbuf (contiguous 12.6MB; both dead by FFN2)
  unsigned short* part01 = (unsigned short*)ln1;

  // fused prolog: qkv-transpose (+bias), W-transposes, LN1 — one launch
  prolog_kernel<<<2752, 256, 0, stream>>>(
      Wq, Wk, Wv, bq, bk, bv, WqkvT, qkvbias,
      W0, W1, W2, W0T, W1T, W2T,
      X, g1, o1, ln1);

  // QKV GEMM with LDS-staged K/V image epilogue (replaces gemm + kvimg)
  gemm_qkv<<<dim3(3 * DD / 128, MM / 128), 256, 0, stream>>>(
      ln1, WqkvT, qkvbias, qbuf, kimg, vimg);
  attn_kernel<<<1536, 128, 0, stream>>>(qbuf, kimg, vimg, attnb);
  // proj via split-K=2 (bf16 partials in part23's two planes)
  gemm_bt_sk<<<dim3(DD / 128, MM / 128, 2), 256, 0, stream>>>(
      attnb, W0T, part23, part23, MM, DD, DD, DD / 2);
  // fused combine + LN2: hbuf (residual for FFN2) + ln2 (FFN1 input)
  combine2_ln<<<MM / 4, 256, 0, stream>>>(
      part23, X, b0, g2, o2, hbuf, ln2);
  gemm_bt<true, true, false><<<dim3(DFF / 128, MM / 128), 256, 0, stream>>>(
      ln2, W1T, b1, nullptr, ffn1, MM, DFF, DD);
  // FFN2 via split-K=4: bf16 partials then combine(+bias+residual)
  gemm_bt_sk<<<dim3(DD / 128, MM / 128, 4), 256, 0, stream>>>(
      ffn1, W2T, part01, part23, MM, DD, DFF, DFF / 4);
  combine4<<<(MM * DD) / 1024, 256, 0, stream>>>(
      part01, part23, hbuf, b2, (float*)d_out, MM * DD, DD);
}

// Round 33
// 177.801 us; speedup vs baseline: 1.0509x; 1.0509x over previous
//
#include <hip/hip_runtime.h>
#include <hip/hip_bf16.h>
#include <cstdint>

// Problem constants
#define BB 2
#define SS 2048
#define DD 768
#define HH 12
#define DHH 64
#define DFF 3072
#define MM (BB * SS)   // 4096

typedef __attribute__((ext_vector_type(8))) short bf16x8;
typedef __attribute__((ext_vector_type(4))) float f32x4;
typedef __attribute__((ext_vector_type(16))) float f32x16;
typedef __attribute__((ext_vector_type(4))) unsigned short u16x4;
typedef __attribute__((ext_vector_type(8))) unsigned short u16x8;
typedef unsigned int u32;

#define DEV static __device__ __forceinline__

typedef __attribute__((address_space(1))) void AS1void;
typedef __attribute__((address_space(3))) void AS3void;

DEV void async_copy16(const void* g, void* l) {
  __builtin_amdgcn_global_load_lds((AS1void*)g, (AS3void*)l, 16, 0, 0);
}

DEV unsigned short bf16bits(float f) {
  __hip_bfloat16 h = __float2bfloat16(f);
  return *(unsigned short*)&h;
}

DEV float bits2f(unsigned short u) {
  u32 x = ((u32)u) << 16;
  union { u32 u; float f; } c; c.u = x;
  return c.f;
}

DEV u32 pack2(float a, float b) {
  return ((u32)bf16bits(b) << 16) | (u32)bf16bits(a);
}

// ---------------- Fused prolog: qkv-transpose + W-transposes + LN1 ----------------
// One launch, 2752 blocks, three independent block-uniform branches:
//   id <  432 : Wq/Wk/Wv [H][D][DH] -> WqkvT [2304][768] (+ qkvbias assembly)
//   id < 1728 : W0/W1/W2 fp32 [R][C] -> bf16 [C][R]
//   else      : LayerNorm1 rows (X -> ln1 bf16), 4 rows/block
// Outputs are disjoint; no intra-kernel dependencies.
__global__ __launch_bounds__(256) void prolog_kernel(
    const float* __restrict__ Wq, const float* __restrict__ Wk,
    const float* __restrict__ Wv, const float* __restrict__ bq,
    const float* __restrict__ bk, const float* __restrict__ bv,
    __hip_bfloat16* __restrict__ WqkvT, float* __restrict__ qkvbias,
    const float* __restrict__ W0, const float* __restrict__ W1,
    const float* __restrict__ W2, __hip_bfloat16* __restrict__ W0T,
    __hip_bfloat16* __restrict__ W1T, __hip_bfloat16* __restrict__ W2T,
    const float* __restrict__ X, const float* __restrict__ g1,
    const float* __restrict__ o1, __hip_bfloat16* __restrict__ ln1)
{
  __shared__ float tile[64][65];
  const int bid = blockIdx.x;

  if (bid < 432) {
    const int y = bid % 12, z = bid / 12;
    const int p = z / HH, h = z - p * HH;
    const float* in = (p == 0 ? Wq : (p == 1 ? Wk : Wv)) + (size_t)h * DD * DHH;
    const int r0 = y * 64;
    if (y == 0 && threadIdx.x < DHH) {
      const float* bsrc = (p == 0 ? bq : (p == 1 ? bk : bv));
      qkvbias[p * DD + h * DHH + threadIdx.x] = bsrc[h * DHH + threadIdx.x];
    }
    for (int i = threadIdx.x; i < 4096; i += 256) {
      int r = i >> 6, c = i & 63;
      tile[r][c] = in[(size_t)(r0 + r) * DHH + c];
    }
    __syncthreads();
    for (int i = threadIdx.x; i < 4096; i += 256) {
      int c = i >> 6, r = i & 63;
      WqkvT[(size_t)(p * DD + h * DHH + c) * DD + r0 + r] = __float2bfloat16(tile[r][c]);
    }
  } else if (bid < 1728) {
    int id = bid - 432;
    const float* in; __hip_bfloat16* out; int R, C, xt, yt;
    if (id < 144)      { in = W0; out = W0T; R = DD;  C = DD;  xt = id % 12; yt = id / 12; }
    else if (id < 720) { id -= 144; in = W1; out = W1T; R = DD;  C = DFF; xt = id % 48; yt = id / 48; }
    else               { id -= 720; in = W2; out = W2T; R = DFF; C = DD;  xt = id % 12; yt = id / 12; }
    const int c0 = xt * 64, r0 = yt * 64;
    for (int i = threadIdx.x; i < 4096; i += 256) {
      int r = i >> 6, c = i & 63;
      tile[r][c] = in[(size_t)(r0 + r) * C + c0 + c];
    }
    __syncthreads();
    for (int i = threadIdx.x; i < 4096; i += 256) {
      int c = i >> 6, r = i & 63;
      out[(size_t)(c0 + c) * R + r0 + r] = __float2bfloat16(tile[r][c]);
    }
  } else {
    const int wave = threadIdx.x >> 6;
    const int lane = threadIdx.x & 63;
    const int row = (bid - 1728) * 4 + wave;
    const float* xr = X + (size_t)row * DD;

    float4 v[3];
    float s1 = 0.f, s2 = 0.f;
#pragma unroll
    for (int j = 0; j < 3; ++j) {
      v[j] = *(const float4*)(xr + (j * 64 + lane) * 4);
      s1 += v[j].x + v[j].y + v[j].z + v[j].w;
      s2 += v[j].x * v[j].x + v[j].y * v[j].y + v[j].z * v[j].z + v[j].w * v[j].w;
    }
#pragma unroll
    for (int d = 1; d < 64; d <<= 1) {
      s1 += __shfl_xor(s1, d);
      s2 += __shfl_xor(s2, d);
    }
    const float mean = s1 * (1.0f / 768.0f);
    const float var = fmaxf(s2 * (1.0f / 768.0f) - mean * mean, 0.0f);
    const float rs = 1.0f / (sqrtf(var) + 1e-5f);

    unsigned short* orow = (unsigned short*)ln1 + (size_t)row * DD;
#pragma unroll
    for (int j = 0; j < 3; ++j) {
      const int c = (j * 64 + lane) * 4;
      float4 g4 = *(const float4*)(g1 + c);
      float4 o4 = *(const float4*)(o1 + c);
      u16x4 pk;
      pk[0] = bf16bits(g4.x * ((v[j].x - mean) * rs) + o4.x);
      pk[1] = bf16bits(g4.y * ((v[j].y - mean) * rs) + o4.y);
      pk[2] = bf16bits(g4.z * ((v[j].z - mean) * rs) + o4.z);
      pk[3] = bf16bits(g4.w * ((v[j].w - mean) * rs) + o4.w);
      *(u16x4*)(orow + c) = pk;
    }
  }
}

// ---------------- K/V FRAGMENT-image builder (verified r13/r17) ----------------
__global__ __launch_bounds__(256) void kvimg_kernel(
    const __hip_bfloat16* __restrict__ qkv, char* __restrict__ kimg,
    char* __restrict__ vimg)
{
  __shared__ unsigned short tileK[64][72];
  __shared__ unsigned short tileV[64][72];
  const int bh = blockIdx.y;
  const int b = bh / HH, h = bh - (bh / HH) * HH;
  const int t0 = blockIdx.x * 64;
  const int HD = 3 * DD;
  const unsigned short* Kp = (const unsigned short*)qkv + (size_t)(b * SS) * HD + DD + h * DHH;
  const unsigned short* Vp = (const unsigned short*)qkv + (size_t)(b * SS) * HD + 2 * DD + h * DHH;
  char* kdst = kimg + ((size_t)bh * 32 + blockIdx.x) * 8192;
  char* vdst = vimg + ((size_t)bh * 32 + blockIdx.x) * 8192;

  for (int i = threadIdx.x; i < 512; i += 256) {
    const int r = i >> 3, c8 = (i & 7) * 8;
    *(bf16x8*)&tileK[r][c8] = *(const bf16x8*)(Kp + (size_t)(t0 + r) * HD + c8);
    *(bf16x8*)&tileV[r][c8] = *(const bf16x8*)(Vp + (size_t)(t0 + r) * HD + c8);
  }
  __syncthreads();
  for (int i = threadIdx.x; i < 512; i += 256) {
    const int f = i >> 6, l = i & 63;
    const int kc = f >> 1, half = f & 1;
    const int lc = l & 31, lh = l >> 5;
    *(bf16x8*)(kdst + i * 16) = *(const bf16x8*)&tileK[half * 32 + lc][kc * 16 + lh * 8];
    union { unsigned short u[8]; bf16x8 v; } w;
#pragma unroll
    for (int e = 0; e < 8; ++e) w.u[e] = tileV[kc * 16 + lh * 8 + e][half * 32 + lc];
    *(bf16x8*)(vdst + i * 16) = w.v;
  }
}

// ---------------- GEMM: bf16 A[M,K] x bf16 BT[N,K], 2-phase dbuf ----------------
template<bool RELU, bool OUT_BF16, bool HAS_RES>
__global__ __launch_bounds__(256) void gemm_bt(
    const __hip_bfloat16* __restrict__ A, const __hip_bfloat16* __restrict__ BT,
    const float* __restrict__ bias, const float* __restrict__ res,
    void* __restrict__ outp, int M, int N, int K)
{
  __shared__ __hip_bfloat16 Alds[2][128 * 32];
  __shared__ __hip_bfloat16 Blds[2][128 * 32];
  const int tid = threadIdx.x;
  const int wave = tid >> 6;
  const int lane = tid & 63;
  const int fr = lane & 15, fq = lane >> 4;
  const int wr = wave >> 1, wc = wave & 1;
  const int bm = blockIdx.y * 128, bn = blockIdx.x * 128;

  const int srow = tid >> 2;
  const int scol = (tid & 3) * 8;
  const __hip_bfloat16* ag0 = A + (size_t)(bm + srow) * K + scol;
  const __hip_bfloat16* ag1 = A + (size_t)(bm + 64 + srow) * K + scol;
  const __hip_bfloat16* bg0 = BT + (size_t)(bn + srow) * K + scol;
  const __hip_bfloat16* bg1 = BT + (size_t)(bn + 64 + srow) * K + scol;
  const int so = wave * 512;

  f32x4 acc[4][4] = {};

  async_copy16(ag0, &Alds[0][so]);
  async_copy16(ag1, &Alds[0][2048 + so]);
  async_copy16(bg0, &Blds[0][so]);
  async_copy16(bg1, &Blds[0][2048 + so]);
  __syncthreads();

  const int niter = K / 32;
  for (int i = 0; i < niter; ++i) {
    const int cur = i & 1;
    if (i + 1 < niter) {
      const int k1 = (i + 1) * 32;
      async_copy16(ag0 + k1, &Alds[cur ^ 1][so]);
      async_copy16(ag1 + k1, &Alds[cur ^ 1][2048 + so]);
      async_copy16(bg0 + k1, &Blds[cur ^ 1][so]);
      async_copy16(bg1 + k1, &Blds[cur ^ 1][2048 + so]);
    }
    bf16x8 af[4], bfr[4];
#pragma unroll
    for (int i4 = 0; i4 < 4; ++i4)
      af[i4] = *(const bf16x8*)(&Alds[cur][(wr * 64 + i4 * 16 + fr) * 32 + fq * 8]);
#pragma unroll
    for (int j4 = 0; j4 < 4; ++j4)
      bfr[j4] = *(const bf16x8*)(&Blds[cur][(wc * 64 + j4 * 16 + fr) * 32 + fq * 8]);
#pragma unroll
    for (int i4 = 0; i4 < 4; ++i4)
#pragma unroll
      for (int j4 = 0; j4 < 4; ++j4)
        acc[i4][j4] = __builtin_amdgcn_mfma_f32_16x16x32_bf16(af[i4], bfr[j4], acc[i4][j4], 0, 0, 0);
    __syncthreads();
  }

#pragma unroll
  for (int j = 0; j < 4; ++j) {
    const int c = bn + wc * 64 + j * 16 + fr;
    const float bv = bias[c];
#pragma unroll
    for (int i = 0; i < 4; ++i) {
#pragma unroll
      for (int r = 0; r < 4; ++r) {
        const int rr = bm + wr * 64 + i * 16 + fq * 4 + r;
        float v = acc[i][j][r] + bv;
        if (RELU) v = fmaxf(v, 0.0f);
        if (HAS_RES) v += res[(size_t)rr * N + c];
        if (OUT_BF16) ((__hip_bfloat16*)outp)[(size_t)rr * N + c] = __float2bfloat16(v);
        else          ((float*)outp)[(size_t)rr * N + c] = v;
      }
    }
  }
}

// ---------------- Split-K GEMM partial (2-phase dbuf): BF16 partial ----------------
// z < 2 -> part01 planes {0,1}; z >= 2 -> part23 planes {0,1}
__global__ __launch_bounds__(256) void gemm_bt_sk(
    const __hip_bfloat16* __restrict__ A, const __hip_bfloat16* __restrict__ BT,
    unsigned short* __restrict__ part01, unsigned short* __restrict__ part23,
    int M, int N, int K, int K_per)
{
  __shared__ __hip_bfloat16 Alds[2][128 * 32];
  __shared__ __hip_bfloat16 Blds[2][128 * 32];
  const int tid = threadIdx.x;
  const int wave = tid >> 6;
  const int lane = tid & 63;
  const int fr = lane & 15, fq = lane >> 4;
  const int wr = wave >> 1, wc = wave & 1;
  const int bm = blockIdx.y * 128, bn = blockIdx.x * 128;
  const int z = blockIdx.z;
  unsigned short* part = (z < 2 ? part01 : part23) + (size_t)(z & 1) * M * N;
  const int kbase = z * K_per;

  const int srow = tid >> 2;
  const int scol = (tid & 3) * 8;
  const __hip_bfloat16* ag0 = A + (size_t)(bm + srow) * K + scol + kbase;
  const __hip_bfloat16* ag1 = A + (size_t)(bm + 64 + srow) * K + scol + kbase;
  const __hip_bfloat16* bg0 = BT + (size_t)(bn + srow) * K + scol + kbase;
  const __hip_bfloat16* bg1 = BT + (size_t)(bn + 64 + srow) * K + scol + kbase;
  const int so = wave * 512;

  f32x4 acc[4][4] = {};

  async_copy16(ag0, &Alds[0][so]);
  async_copy16(ag1, &Alds[0][2048 + so]);
  async_copy16(bg0, &Blds[0][so]);
  async_copy16(bg1, &Blds[0][2048 + so]);
  __syncthreads();

  const int niter = K_per / 32;
  for (int i = 0; i < niter; ++i) {
    const int cur = i & 1;
    if (i + 1 < niter) {
      const int k1 = (i + 1) * 32;
      async_copy16(ag0 + k1, &Alds[cur ^ 1][so]);
      async_copy16(ag1 + k1, &Alds[cur ^ 1][2048 + so]);
      async_copy16(bg0 + k1, &Blds[cur ^ 1][so]);
      async_copy16(bg1 + k1, &Blds[cur ^ 1][2048 + so]);
    }
    bf16x8 af[4], bfr[4];
#pragma unroll
    for (int i4 = 0; i4 < 4; ++i4)
      af[i4] = *(const bf16x8*)(&Alds[cur][(wr * 64 + i4 * 16 + fr) * 32 + fq * 8]);
#pragma unroll
    for (int j4 = 0; j4 < 4; ++j4)
      bfr[j4] = *(const bf16x8*)(&Blds[cur][(wc * 64 + j4 * 16 + fr) * 32 + fq * 8]);
#pragma unroll
    for (int i4 = 0; i4 < 4; ++i4)
#pragma unroll
      for (int j4 = 0; j4 < 4; ++j4)
        acc[i4][j4] = __builtin_amdgcn_mfma_f32_16x16x32_bf16(af[i4], bfr[j4], acc[i4][j4], 0, 0, 0);
    __syncthreads();
  }

#pragma unroll
  for (int j = 0; j < 4; ++j) {
    const int c = bn + wc * 64 + j * 16 + fr;
#pragma unroll
    for (int i = 0; i < 4; ++i) {
#pragma unroll
      for (int r = 0; r < 4; ++r) {
        const int rr = bm + wr * 64 + i * 16 + fq * 4 + r;
        part[(size_t)rr * N + c] = bf16bits(acc[i][j][r]);
      }
    }
  }
}

// ---------------- combine 4 bf16 split-K partials + bias + residual -> fp32 ----------------
__global__ __launch_bounds__(256) void combine4(
    const unsigned short* __restrict__ part01, const unsigned short* __restrict__ part23,
    const float* __restrict__ res, const float* __restrict__ bias,
    float* __restrict__ out, int MN, int N)
{
  const int idx = (blockIdx.x * 256 + threadIdx.x) * 4;
  if (idx >= MN) return;
  const u16x4 a0 = *(const u16x4*)(part01 + idx);
  const u16x4 a1 = *(const u16x4*)(part01 + MN + idx);
  const u16x4 a2 = *(const u16x4*)(part23 + idx);
  const u16x4 a3 = *(const u16x4*)(part23 + MN + idx);
  const float4 rr = *(const float4*)(res + idx);
  const float4 bb = *(const float4*)(bias + (idx % N));
  float4 o;
  o.x = bits2f(a0[0]) + bits2f(a1[0]) + bits2f(a2[0]) + bits2f(a3[0]) + rr.x + bb.x;
  o.y = bits2f(a0[1]) + bits2f(a1[1]) + bits2f(a2[1]) + bits2f(a3[1]) + rr.y + bb.y;
  o.z = bits2f(a0[2]) + bits2f(a1[2]) + bits2f(a2[2]) + bits2f(a3[2]) + rr.z + bb.z;
  o.w = bits2f(a0[3]) + bits2f(a1[3]) + bits2f(a2[3]) + bits2f(a3[3]) + rr.w + bb.w;
  *(float4*)(out + idx) = o;
}

// ---------------- fused: combine 2 bf16 partials + bias + residual -> hbuf, then LN -> bf16 ----------------
__global__ __launch_bounds__(256) void combine2_ln(
    const unsigned short* __restrict__ part, const float* __restrict__ res,
    const float* __restrict__ bias, const float* __restrict__ gain,
    const float* __restrict__ off, float* __restrict__ hout,
    __hip_bfloat16* __restrict__ lnout)
{
  const int wave = threadIdx.x >> 6;
  const int lane = threadIdx.x & 63;
  const int row = blockIdx.x * 4 + wave;
  const int MN = MM * DD;
  const size_t rbase = (size_t)row * DD;

  float v[3][4];
  float s1 = 0.f, s2 = 0.f;
#pragma unroll
  for (int j = 0; j < 3; ++j) {
    const int c = (j * 64 + lane) * 4;
    const size_t idx = rbase + c;
    const u16x4 a0 = *(const u16x4*)(part + idx);
    const u16x4 a1 = *(const u16x4*)(part + MN + idx);
    const float4 rr = *(const float4*)(res + idx);
    const float4 bb = *(const float4*)(bias + c);
    v[j][0] = bits2f(a0[0]) + bits2f(a1[0]) + rr.x + bb.x;
    v[j][1] = bits2f(a0[1]) + bits2f(a1[1]) + rr.y + bb.y;
    v[j][2] = bits2f(a0[2]) + bits2f(a1[2]) + rr.z + bb.z;
    v[j][3] = bits2f(a0[3]) + bits2f(a1[3]) + rr.w + bb.w;
    float4 hv = { v[j][0], v[j][1], v[j][2], v[j][3] };
    *(float4*)(hout + idx) = hv;
    s1 += v[j][0] + v[j][1] + v[j][2] + v[j][3];
    s2 += v[j][0]*v[j][0] + v[j][1]*v[j][1] + v[j][2]*v[j][2] + v[j][3]*v[j][3];
  }
#pragma unroll
  for (int d = 1; d < 64; d <<= 1) {
    s1 += __shfl_xor(s1, d);
    s2 += __shfl_xor(s2, d);
  }
  const float mean = s1 * (1.0f / 768.0f);
  const float var = fmaxf(s2 * (1.0f / 768.0f) - mean * mean, 0.0f);
  const float rs = 1.0f / (sqrtf(var) + 1e-5f);

  unsigned short* orow = (unsigned short*)lnout + rbase;
#pragma unroll
  for (int j = 0; j < 3; ++j) {
    const int c = (j * 64 + lane) * 4;
    const float4 g4 = *(const float4*)(gain + c);
    const float4 o4 = *(const float4*)(off + c);
    u16x4 pk;
    pk[0] = bf16bits(g4.x * ((v[j][0] - mean) * rs) + o4.x);
    pk[1] = bf16bits(g4.y * ((v[j][1] - mean) * rs) + o4.y);
    pk[2] = bf16bits(g4.z * ((v[j][2] - mean) * rs) + o4.z);
    pk[3] = bf16bits(g4.w * ((v[j][3] - mean) * rs) + o4.w);
    *(u16x4*)(orow + c) = pk;
  }
}

// ---------------- Flash attention: register-fragment streams + K-prefetch (r18/r24) ----------------
// 1536 blocks x 128 threads (2 warps = one 32-row q strip, kv-split 2).
// QK^T(t) first (K resident from t-2 prefetch); then V(t) + K(t+2) loads issue,
// hiding under softmax+PV. setprio(1) wraps MFMA clusters. LDS only for the
// final LSE combine. Concurrency is register-capped at ~3 waves/SIMD;
// launch_bounds(128,3) + serial (register-lean) reductions is the proven
// no-spill config — tree reductions spill (r25).
__global__ __launch_bounds__(128, 3) void attn_kernel(
    const __hip_bfloat16* __restrict__ qkv, const char* __restrict__ kimg,
    const char* __restrict__ vimg, __hip_bfloat16* __restrict__ outp)
{
  const int HD = 3 * DD;   // 2304
  const int id = blockIdx.x;          // 0..1535
  const int xcd = id & 7;
  const int j = id >> 3;              // 0..191 within XCD
  const int s2 = 63 - j / 3;          // strip 0..63, heavy first
  const int bhl = j - 3 * (j / 3);
  const int bh = xcd * 3 + bhl;       // 24 heads = 8 XCD x 3
  const int b = bh / HH, h = bh - (bh / HH) * HH;

  const int q0w = s2 * 32;
  const int tid = threadIdx.x;
  const int c = tid >> 6;             // warp = kv-split index 0/1
  const int lane = tid & 63;
  const int col = lane & 31, hi = lane >> 5;
  const int qg = q0w + col;

  const size_t base = (size_t)b * SS * HD;
  const __hip_bfloat16* Qp = qkv + base + h * DHH;
  const char* kimg_h = kimg + (size_t)bh * 32 * 8192;
  const char* vimg_h = vimg + (size_t)bh * 32 * 8192;

  __shared__ __align__(16) char sm[17408];

  bf16x8 qf[4];
#pragma unroll
  for (int kc = 0; kc < 4; ++kc)
    qf[kc] = *(const bf16x8*)(Qp + (size_t)qg * HD + kc * 16 + hi * 8);

  f32x16 o0 = {}, o1 = {};
  float mreg = -1e30f, lreg = 0.f;
  const float CS = 0.125f * 1.44269504f;   // (1/sqrt(64)) * log2(e)

  const int ntiles = (q0w >> 6) + 1;

  // prologue: K fragments of first tile
  bf16x8 kf[8];
  {
    const char* ks = kimg_h + (size_t)c * 8192 + lane * 16;
#pragma unroll
    for (int f = 0; f < 8; ++f) kf[f] = *(const bf16x8*)(ks + f * 1024);
  }

  for (int t = c; t < ntiles; t += 2) {
    const int kv0 = t * 64;
    // ---- QK^T (swapped): D col = q (lane-local) ----
    f32x16 s0 = {}, s1 = {};
    __builtin_amdgcn_s_setprio(1);
#pragma unroll
    for (int kc = 0; kc < 4; ++kc) {
      s0 = __builtin_amdgcn_mfma_f32_32x32x16_bf16(kf[kc * 2],     qf[kc], s0, 0, 0, 0);
      s1 = __builtin_amdgcn_mfma_f32_32x32x16_bf16(kf[kc * 2 + 1], qf[kc], s1, 0, 0, 0);
    }
    __builtin_amdgcn_s_setprio(0);
    // ---- issue V loads for this tile AND K loads for tile t+2 ----
    bf16x8 vf[8];
    {
      const char* vs = vimg_h + (size_t)t * 8192 + lane * 16;
#pragma unroll
      for (int f = 0; f < 8; ++f) vf[f] = *(const bf16x8*)(vs + f * 1024);
    }
    if (t + 2 < ntiles) {
      const char* ks = kimg_h + (size_t)(t + 2) * 8192 + lane * 16;
#pragma unroll
      for (int f = 0; f < 8; ++f) kf[f] = *(const bf16x8*)(ks + f * 1024);
    }
    // ---- causal mask (diagonal tile only) ----
    if (kv0 + 63 > q0w) {
#pragma unroll
      for (int r = 0; r < 16; ++r) {
        const int tl = (r & 3) + 8 * (r >> 2) + 4 * hi;
        s0[r] = (kv0 + tl <= qg) ? s0[r] : -1e30f;
        s1[r] = (kv0 + 32 + tl <= qg) ? s1[r] : -1e30f;
      }
    }
    // ---- online softmax, fully in-register ----
    float mx = s0[0];
#pragma unroll
    for (int r = 1; r < 16; ++r) mx = fmaxf(mx, s0[r]);
#pragma unroll
    for (int r = 0; r < 16; ++r) mx = fmaxf(mx, s1[r]);
    mx = fmaxf(mx, __shfl_xor(mx, 32));
    const float mnew = fmaxf(mreg, mx);
    const float alpha = exp2f((mreg - mnew) * CS);
    mreg = mnew;
    const float mc = mnew * CS;
    float ps = 0.f;
#pragma unroll
    for (int r = 0; r < 16; ++r) {
      const float p0 = exp2f(s0[r] * CS - mc); s0[r] = p0; ps += p0;
      const float p1 = exp2f(s1[r] * CS - mc); s1[r] = p1; ps += p1;
    }
    ps += __shfl_xor(ps, 32);
    lreg = lreg * alpha + ps;
#pragma unroll
    for (int r = 0; r < 16; ++r) { o0[r] *= alpha; o1[r] *= alpha; }

    // ---- pack P rows to bf16 pairs ----
    u32 pk0[4][2], pk1[4][2];
#pragma unroll
    for (int qd = 0; qd < 4; ++qd) {
      pk0[qd][0] = pack2(s0[4 * qd + 0], s0[4 * qd + 1]);
      pk0[qd][1] = pack2(s0[4 * qd + 2], s0[4 * qd + 3]);
      pk1[qd][0] = pack2(s1[4 * qd + 0], s1[4 * qd + 1]);
      pk1[qd][1] = pack2(s1[4 * qd + 2], s1[4 * qd + 3]);
    }
    // ---- PV: O += mfma(V-frag (A), P-frag (B)) ----
#pragma unroll
    for (int kc = 0; kc < 4; ++kc) {
      const int qa = 2 * (kc & 1), qb = qa + 1;
      const u32 A0 = (kc < 2) ? pk0[qa][0] : pk1[qa][0];
      const u32 A1 = (kc < 2) ? pk0[qa][1] : pk1[qa][1];
      const u32 B0 = (kc < 2) ? pk0[qb][0] : pk1[qb][0];
      const u32 B1 = (kc < 2) ? pk0[qb][1] : pk1[qb][1];
      const u32 send0 = hi ? A0 : B0;
      const u32 send1 = hi ? A1 : B1;
      const u32 recv0 = __shfl_xor(send0, 32);
      const u32 recv1 = __shfl_xor(send1, 32);
      const u32 su0 = hi ? B0 : A0;
      const u32 su1 = hi ? B1 : A1;
      union { u32 u[4]; bf16x8 v; } pf;
      pf.u[0] = hi ? recv0 : su0;
      pf.u[1] = hi ? recv1 : su1;
      pf.u[2] = hi ? su0 : recv0;
      pf.u[3] = hi ? su1 : recv1;
      __builtin_amdgcn_s_setprio(1);
      o0 = __builtin_amdgcn_mfma_f32_32x32x16_bf16(vf[kc * 2],     pf.v, o0, 0, 0, 0);
      o1 = __builtin_amdgcn_mfma_f32_32x32x16_bf16(vf[kc * 2 + 1], pf.v, o1, 0, 0, 0);
      __builtin_amdgcn_s_setprio(0);
    }
  }

  // ---- combine the 2 kv-split partials via LDS (1 barrier) ----
  float* opart = (float*)sm;                 // [2][32][65]
  float* mlp   = (float*)(sm + 16640);       // [c][0][q]=m, [c][1][q]=l
#pragma unroll
  for (int r = 0; r < 16; ++r) {
    const int d = (r & 3) + 8 * (r >> 2) + 4 * hi;
    opart[(c * 32 + col) * 65 + d]      = o0[r];
    opart[(c * 32 + col) * 65 + d + 32] = o1[r];
  }
  if (hi == 0) {
    mlp[c * 64 + col]      = mreg;
    mlp[c * 64 + 32 + col] = lreg;
  }
  __syncthreads();

  const int q = tid >> 2;            // 0..31
  const int d0 = (tid & 3) * 16;     // 0..48
  float mcv[2], lcv[2];
#pragma unroll
  for (int cc = 0; cc < 2; ++cc) {
    mcv[cc] = mlp[cc * 64 + q];
    lcv[cc] = mlp[cc * 64 + 32 + q];
  }
  const float mstar = fmaxf(mcv[0], mcv[1]);
  float av[2], lstar = 0.f;
#pragma unroll
  for (int cc = 0; cc < 2; ++cc) {
    av[cc] = exp2f((mcv[cc] - mstar) * CS);
    lstar += av[cc] * lcv[cc];
  }
  const float inv = 1.0f / lstar;
  float acc[16] = {};
#pragma unroll
  for (int cc = 0; cc < 2; ++cc) {
    const float a = av[cc];
#pragma unroll
    for (int e = 0; e < 16; ++e)
      acc[e] += a * opart[(cc * 32 + q) * 65 + d0 + e];
  }
  unsigned short* orow = (unsigned short*)outp +
      (size_t)(b * SS + q0w + q) * DD + h * DHH + d0;
  u16x8 w8;
#pragma unroll
  for (int e = 0; e < 8; ++e) w8[e] = bf16bits(acc[e] * inv);
  *(u16x8*)orow = w8;
#pragma unroll
  for (int e = 0; e < 8; ++e) w8[e] = bf16bits(acc[8 + e] * inv);
  *(u16x8*)(orow + 8) = w8;
}

// ---------------- host ----------------
extern "C" void kernel_launch(void* const* d_in, const int* in_sizes, int n_in,
                              void* d_out, int out_size, void* d_ws, size_t ws_size,
                              hipStream_t stream)
{
  (void)in_sizes; (void)n_in; (void)out_size; (void)ws_size;
  const float* X  = (const float*)d_in[0];
  const float* Wq = (const float*)d_in[1];
  const float* bq = (const float*)d_in[2];
  const float* Wk = (const float*)d_in[3];
  const float* bk = (const float*)d_in[4];
  const float* Wv = (const float*)d_in[5];
  const float* bv = (const float*)d_in[6];
  const float* W0 = (const float*)d_in[7];
  const float* b0 = (const float*)d_in[8];
  const float* W1 = (const float*)d_in[9];
  const float* b1 = (const float*)d_in[10];
  const float* W2 = (const float*)d_in[11];
  const float* b2 = (const float*)d_in[12];
  const float* g1 = (const float*)d_in[13];
  const float* o1 = (const float*)d_in[14];
  const float* g2 = (const float*)d_in[15];
  const float* o2 = (const float*)d_in[16];

  char* ws = (char*)d_ws;
  auto alloc = [&](size_t bytes) {
    char* p = ws;
    ws += (bytes + 255) & ~(size_t)255;
    return p;
  };
  __hip_bfloat16* ln1    = (__hip_bfloat16*)alloc((size_t)MM * DD * 2);
  __hip_bfloat16* qkvb16 = (__hip_bfloat16*)alloc((size_t)MM * 3 * DD * 2);
  __hip_bfloat16* attnb  = (__hip_bfloat16*)alloc((size_t)MM * DD * 2);
  float*          hbuf   = (float*)alloc((size_t)MM * DD * 4);
  __hip_bfloat16* ln2    = (__hip_bfloat16*)alloc((size_t)MM * DD * 2);
  __hip_bfloat16* ffn1   = (__hip_bfloat16*)alloc((size_t)MM * DFF * 2);
  __hip_bfloat16* WqkvT  = (__hip_bfloat16*)alloc((size_t)3 * DD * DD * 2);
  __hip_bfloat16* W0T    = (__hip_bfloat16*)alloc((size_t)DD * DD * 2);
  __hip_bfloat16* W1T    = (__hip_bfloat16*)alloc((size_t)DFF * DD * 2);
  __hip_bfloat16* W2T    = (__hip_bfloat16*)alloc((size_t)DD * DFF * 2);
  float*          qkvbias= (float*)alloc((size_t)3 * DD * 4);
  unsigned short* part23 = (unsigned short*)alloc((size_t)2 * MM * DD * 2);  // 2 bf16 planes
  char*           kimg   = alloc((size_t)24 * 32 * 8192);           // K fragment images
  char*           vimg   = alloc((size_t)24 * 32 * 8192);           // V fragment images
  // bf16 FFN2 splits 0,1 alias ln1 (+ spill into qkvb16; both dead by FFN2)
  unsigned short* part01 = (unsigned short*)ln1;

  // fused prolog: qkv-transpose (+bias), W-transposes, LN1 — one launch
  prolog_kernel<<<2752, 256, 0, stream>>>(
      Wq, Wk, Wv, bq, bk, bv, WqkvT, qkvbias,
      W0, W1, W2, W0T, W1T, W2T,
      X, g1, o1, ln1);

  gemm_bt<false, true, false><<<dim3(3 * DD / 128, MM / 128), 256, 0, stream>>>(
      ln1, WqkvT, qkvbias, nullptr, qkvb16, MM, 3 * DD, DD);
  kvimg_kernel<<<dim3(SS / 64, BB * HH), 256, 0, stream>>>(qkvb16, kimg, vimg);
  attn_kernel<<<1536, 128, 0, stream>>>(qkvb16, kimg, vimg, attnb);
  // proj via split-K=2 (bf16 partials in part23's two planes)
  gemm_bt_sk<<<dim3(DD / 128, MM / 128, 2), 256, 0, stream>>>(
      attnb, W0T, part23, part23, MM, DD, DD, DD / 2);
  // fused combine + LN2: hbuf (residual for FFN2) + ln2 (FFN1 input)
  combine2_ln<<<MM / 4, 256, 0, stream>>>(
      part23, X, b0, g2, o2, hbuf, ln2);
  gemm_bt<true, true, false><<<dim3(DFF / 128, MM / 128), 256, 0, stream>>>(
      ln2, W1T, b1, nullptr, ffn1, MM, DFF, DD);
  // FFN2 via split-K=4: bf16 partials then combine(+bias+residual)
  gemm_bt_sk<<<dim3(DD / 128, MM / 128, 4), 256, 0, stream>>>(
      ffn1, W2T, part01, part23, MM, DD, DFF, DFF / 4);
  combine4<<<(MM * DD) / 1024, 256, 0, stream>>>(
      part01, part23, hbuf, b2, (float*)d_out, MM * DD, DD);
}

// Round 34
// 172.566 us; speedup vs baseline: 1.0827x; 1.0303x over previous
//
#include <hip/hip_runtime.h>
#include <hip/hip_bf16.h>
#include <cstdint>

// Problem constants
#define BB 2
#define SS 2048
#define DD 768
#define HH 12
#define DHH 64
#define DFF 3072
#define MM (BB * SS)   // 4096

typedef __attribute__((ext_vector_type(8))) short bf16x8;
typedef __attribute__((ext_vector_type(4))) float f32x4;
typedef __attribute__((ext_vector_type(16))) float f32x16;
typedef __attribute__((ext_vector_type(4))) unsigned short u16x4;
typedef __attribute__((ext_vector_type(8))) unsigned short u16x8;
typedef unsigned int u32;

#define DEV static __device__ __forceinline__

typedef __attribute__((address_space(1))) void AS1void;
typedef __attribute__((address_space(3))) void AS3void;

DEV void async_copy16(const void* g, void* l) {
  __builtin_amdgcn_global_load_lds((AS1void*)g, (AS3void*)l, 16, 0, 0);
}

DEV unsigned short bf16bits(float f) {
  __hip_bfloat16 h = __float2bfloat16(f);
  return *(unsigned short*)&h;
}

DEV float bits2f(unsigned short u) {
  u32 x = ((u32)u) << 16;
  union { u32 u; float f; } c; c.u = x;
  return c.f;
}

DEV u32 pack2(float a, float b) {
  return ((u32)bf16bits(b) << 16) | (u32)bf16bits(a);
}

// ---------------- Fused prolog: qkv-transpose + W-transposes + LN1 ----------------
__global__ __launch_bounds__(256) void prolog_kernel(
    const float* __restrict__ Wq, const float* __restrict__ Wk,
    const float* __restrict__ Wv, const float* __restrict__ bq,
    const float* __restrict__ bk, const float* __restrict__ bv,
    __hip_bfloat16* __restrict__ WqkvT, float* __restrict__ qkvbias,
    const float* __restrict__ W0, const float* __restrict__ W1,
    const float* __restrict__ W2, __hip_bfloat16* __restrict__ W0T,
    __hip_bfloat16* __restrict__ W1T, __hip_bfloat16* __restrict__ W2T,
    const float* __restrict__ X, const float* __restrict__ g1,
    const float* __restrict__ o1, __hip_bfloat16* __restrict__ ln1)
{
  __shared__ float tile[64][65];
  const int bid = blockIdx.x;

  if (bid < 432) {
    const int y = bid % 12, z = bid / 12;
    const int p = z / HH, h = z - p * HH;
    const float* in = (p == 0 ? Wq : (p == 1 ? Wk : Wv)) + (size_t)h * DD * DHH;
    const int r0 = y * 64;
    if (y == 0 && threadIdx.x < DHH) {
      const float* bsrc = (p == 0 ? bq : (p == 1 ? bk : bv));
      qkvbias[p * DD + h * DHH + threadIdx.x] = bsrc[h * DHH + threadIdx.x];
    }
    for (int i = threadIdx.x; i < 4096; i += 256) {
      int r = i >> 6, c = i & 63;
      tile[r][c] = in[(size_t)(r0 + r) * DHH + c];
    }
    __syncthreads();
    for (int i = threadIdx.x; i < 4096; i += 256) {
      int c = i >> 6, r = i & 63;
      WqkvT[(size_t)(p * DD + h * DHH + c) * DD + r0 + r] = __float2bfloat16(tile[r][c]);
    }
  } else if (bid < 1728) {
    int id = bid - 432;
    const float* in; __hip_bfloat16* out; int R, C, xt, yt;
    if (id < 144)      { in = W0; out = W0T; R = DD;  C = DD;  xt = id % 12; yt = id / 12; }
    else if (id < 720) { id -= 144; in = W1; out = W1T; R = DD;  C = DFF; xt = id % 48; yt = id / 48; }
    else               { id -= 720; in = W2; out = W2T; R = DFF; C = DD;  xt = id % 12; yt = id / 12; }
    const int c0 = xt * 64, r0 = yt * 64;
    for (int i = threadIdx.x; i < 4096; i += 256) {
      int r = i >> 6, c = i & 63;
      tile[r][c] = in[(size_t)(r0 + r) * C + c0 + c];
    }
    __syncthreads();
    for (int i = threadIdx.x; i < 4096; i += 256) {
      int c = i >> 6, r = i & 63;
      out[(size_t)(c0 + c) * R + r0 + r] = __float2bfloat16(tile[r][c]);
    }
  } else {
    const int wave = threadIdx.x >> 6;
    const int lane = threadIdx.x & 63;
    const int row = (bid - 1728) * 4 + wave;
    const float* xr = X + (size_t)row * DD;

    float4 v[3];
    float s1 = 0.f, s2 = 0.f;
#pragma unroll
    for (int j = 0; j < 3; ++j) {
      v[j] = *(const float4*)(xr + (j * 64 + lane) * 4);
      s1 += v[j].x + v[j].y + v[j].z + v[j].w;
      s2 += v[j].x * v[j].x + v[j].y * v[j].y + v[j].z * v[j].z + v[j].w * v[j].w;
    }
#pragma unroll
    for (int d = 1; d < 64; d <<= 1) {
      s1 += __shfl_xor(s1, d);
      s2 += __shfl_xor(s2, d);
    }
    const float mean = s1 * (1.0f / 768.0f);
    const float var = fmaxf(s2 * (1.0f / 768.0f) - mean * mean, 0.0f);
    const float rs = 1.0f / (sqrtf(var) + 1e-5f);

    unsigned short* orow = (unsigned short*)ln1 + (size_t)row * DD;
#pragma unroll
    for (int j = 0; j < 3; ++j) {
      const int c = (j * 64 + lane) * 4;
      float4 g4 = *(const float4*)(g1 + c);
      float4 o4 = *(const float4*)(o1 + c);
      u16x4 pk;
      pk[0] = bf16bits(g4.x * ((v[j].x - mean) * rs) + o4.x);
      pk[1] = bf16bits(g4.y * ((v[j].y - mean) * rs) + o4.y);
      pk[2] = bf16bits(g4.z * ((v[j].z - mean) * rs) + o4.z);
      pk[3] = bf16bits(g4.w * ((v[j].w - mean) * rs) + o4.w);
      *(u16x4*)(orow + c) = pk;
    }
  }
}

// ---------------- K/V FRAGMENT-image builder (verified r13/r17) ----------------
__global__ __launch_bounds__(256) void kvimg_kernel(
    const __hip_bfloat16* __restrict__ qkv, char* __restrict__ kimg,
    char* __restrict__ vimg)
{
  __shared__ unsigned short tileK[64][72];
  __shared__ unsigned short tileV[64][72];
  const int bh = blockIdx.y;
  const int b = bh / HH, h = bh - (bh / HH) * HH;
  const int t0 = blockIdx.x * 64;
  const int HD = 3 * DD;
  const unsigned short* Kp = (const unsigned short*)qkv + (size_t)(b * SS) * HD + DD + h * DHH;
  const unsigned short* Vp = (const unsigned short*)qkv + (size_t)(b * SS) * HD + 2 * DD + h * DHH;
  char* kdst = kimg + ((size_t)bh * 32 + blockIdx.x) * 8192;
  char* vdst = vimg + ((size_t)bh * 32 + blockIdx.x) * 8192;

  for (int i = threadIdx.x; i < 512; i += 256) {
    const int r = i >> 3, c8 = (i & 7) * 8;
    *(bf16x8*)&tileK[r][c8] = *(const bf16x8*)(Kp + (size_t)(t0 + r) * HD + c8);
    *(bf16x8*)&tileV[r][c8] = *(const bf16x8*)(Vp + (size_t)(t0 + r) * HD + c8);
  }
  __syncthreads();
  for (int i = threadIdx.x; i < 512; i += 256) {
    const int f = i >> 6, l = i & 63;
    const int kc = f >> 1, half = f & 1;
    const int lc = l & 31, lh = l >> 5;
    *(bf16x8*)(kdst + i * 16) = *(const bf16x8*)&tileK[half * 32 + lc][kc * 16 + lh * 8];
    union { unsigned short u[8]; bf16x8 v; } w;
#pragma unroll
    for (int e = 0; e < 8; ++e) w.u[e] = tileV[kc * 16 + lh * 8 + e][half * 32 + lc];
    *(bf16x8*)(vdst + i * 16) = w.v;
  }
}

// ---------------- GEMM: bf16 A[M,K] x bf16 BT[N,K], 2-phase dbuf ----------------
template<bool RELU, bool OUT_BF16, bool HAS_RES>
__global__ __launch_bounds__(256) void gemm_bt(
    const __hip_bfloat16* __restrict__ A, const __hip_bfloat16* __restrict__ BT,
    const float* __restrict__ bias, const float* __restrict__ res,
    void* __restrict__ outp, int M, int N, int K)
{
  __shared__ __hip_bfloat16 Alds[2][128 * 32];
  __shared__ __hip_bfloat16 Blds[2][128 * 32];
  const int tid = threadIdx.x;
  const int wave = tid >> 6;
  const int lane = tid & 63;
  const int fr = lane & 15, fq = lane >> 4;
  const int wr = wave >> 1, wc = wave & 1;
  const int bm = blockIdx.y * 128, bn = blockIdx.x * 128;

  const int srow = tid >> 2;
  const int scol = (tid & 3) * 8;
  const __hip_bfloat16* ag0 = A + (size_t)(bm + srow) * K + scol;
  const __hip_bfloat16* ag1 = A + (size_t)(bm + 64 + srow) * K + scol;
  const __hip_bfloat16* bg0 = BT + (size_t)(bn + srow) * K + scol;
  const __hip_bfloat16* bg1 = BT + (size_t)(bn + 64 + srow) * K + scol;
  const int so = wave * 512;

  f32x4 acc[4][4] = {};

  async_copy16(ag0, &Alds[0][so]);
  async_copy16(ag1, &Alds[0][2048 + so]);
  async_copy16(bg0, &Blds[0][so]);
  async_copy16(bg1, &Blds[0][2048 + so]);
  __syncthreads();

  const int niter = K / 32;
  for (int i = 0; i < niter; ++i) {
    const int cur = i & 1;
    if (i + 1 < niter) {
      const int k1 = (i + 1) * 32;
      async_copy16(ag0 + k1, &Alds[cur ^ 1][so]);
      async_copy16(ag1 + k1, &Alds[cur ^ 1][2048 + so]);
      async_copy16(bg0 + k1, &Blds[cur ^ 1][so]);
      async_copy16(bg1 + k1, &Blds[cur ^ 1][2048 + so]);
    }
    bf16x8 af[4], bfr[4];
#pragma unroll
    for (int i4 = 0; i4 < 4; ++i4)
      af[i4] = *(const bf16x8*)(&Alds[cur][(wr * 64 + i4 * 16 + fr) * 32 + fq * 8]);
#pragma unroll
    for (int j4 = 0; j4 < 4; ++j4)
      bfr[j4] = *(const bf16x8*)(&Blds[cur][(wc * 64 + j4 * 16 + fr) * 32 + fq * 8]);
#pragma unroll
    for (int i4 = 0; i4 < 4; ++i4)
#pragma unroll
      for (int j4 = 0; j4 < 4; ++j4)
        acc[i4][j4] = __builtin_amdgcn_mfma_f32_16x16x32_bf16(af[i4], bfr[j4], acc[i4][j4], 0, 0, 0);
    __syncthreads();
  }

#pragma unroll
  for (int j = 0; j < 4; ++j) {
    const int c = bn + wc * 64 + j * 16 + fr;
    const float bv = bias[c];
#pragma unroll
    for (int i = 0; i < 4; ++i) {
#pragma unroll
      for (int r = 0; r < 4; ++r) {
        const int rr = bm + wr * 64 + i * 16 + fq * 4 + r;
        float v = acc[i][j][r] + bv;
        if (RELU) v = fmaxf(v, 0.0f);
        if (HAS_RES) v += res[(size_t)rr * N + c];
        if (OUT_BF16) ((__hip_bfloat16*)outp)[(size_t)rr * N + c] = __float2bfloat16(v);
        else          ((float*)outp)[(size_t)rr * N + c] = v;
      }
    }
  }
}

// ---------------- Split-K GEMM partial (2-phase dbuf): BF16 partial ----------------
// z < 2 -> part01 planes {0,1}; z >= 2 -> part23 planes {0,1}
__global__ __launch_bounds__(256) void gemm_bt_sk(
    const __hip_bfloat16* __restrict__ A, const __hip_bfloat16* __restrict__ BT,
    unsigned short* __restrict__ part01, unsigned short* __restrict__ part23,
    int M, int N, int K, int K_per)
{
  __shared__ __hip_bfloat16 Alds[2][128 * 32];
  __shared__ __hip_bfloat16 Blds[2][128 * 32];
  const int tid = threadIdx.x;
  const int wave = tid >> 6;
  const int lane = tid & 63;
  const int fr = lane & 15, fq = lane >> 4;
  const int wr = wave >> 1, wc = wave & 1;
  const int bm = blockIdx.y * 128, bn = blockIdx.x * 128;
  const int z = blockIdx.z;
  unsigned short* part = (z < 2 ? part01 : part23) + (size_t)(z & 1) * M * N;
  const int kbase = z * K_per;

  const int srow = tid >> 2;
  const int scol = (tid & 3) * 8;
  const __hip_bfloat16* ag0 = A + (size_t)(bm + srow) * K + scol + kbase;
  const __hip_bfloat16* ag1 = A + (size_t)(bm + 64 + srow) * K + scol + kbase;
  const __hip_bfloat16* bg0 = BT + (size_t)(bn + srow) * K + scol + kbase;
  const __hip_bfloat16* bg1 = BT + (size_t)(bn + 64 + srow) * K + scol + kbase;
  const int so = wave * 512;

  f32x4 acc[4][4] = {};

  async_copy16(ag0, &Alds[0][so]);
  async_copy16(ag1, &Alds[0][2048 + so]);
  async_copy16(bg0, &Blds[0][so]);
  async_copy16(bg1, &Blds[0][2048 + so]);
  __syncthreads();

  const int niter = K_per / 32;
  for (int i = 0; i < niter; ++i) {
    const int cur = i & 1;
    if (i + 1 < niter) {
      const int k1 = (i + 1) * 32;
      async_copy16(ag0 + k1, &Alds[cur ^ 1][so]);
      async_copy16(ag1 + k1, &Alds[cur ^ 1][2048 + so]);
      async_copy16(bg0 + k1, &Blds[cur ^ 1][so]);
      async_copy16(bg1 + k1, &Blds[cur ^ 1][2048 + so]);
    }
    bf16x8 af[4], bfr[4];
#pragma unroll
    for (int i4 = 0; i4 < 4; ++i4)
      af[i4] = *(const bf16x8*)(&Alds[cur][(wr * 64 + i4 * 16 + fr) * 32 + fq * 8]);
#pragma unroll
    for (int j4 = 0; j4 < 4; ++j4)
      bfr[j4] = *(const bf16x8*)(&Blds[cur][(wc * 64 + j4 * 16 + fr) * 32 + fq * 8]);
#pragma unroll
    for (int i4 = 0; i4 < 4; ++i4)
#pragma unroll
      for (int j4 = 0; j4 < 4; ++j4)
        acc[i4][j4] = __builtin_amdgcn_mfma_f32_16x16x32_bf16(af[i4], bfr[j4], acc[i4][j4], 0, 0, 0);
    __syncthreads();
  }

#pragma unroll
  for (int j = 0; j < 4; ++j) {
    const int c = bn + wc * 64 + j * 16 + fr;
#pragma unroll
    for (int i = 0; i < 4; ++i) {
#pragma unroll
      for (int r = 0; r < 4; ++r) {
        const int rr = bm + wr * 64 + i * 16 + fq * 4 + r;
        part[(size_t)rr * N + c] = bf16bits(acc[i][j][r]);
      }
    }
  }
}

// ---------------- combine 4 bf16 split-K partials + bias + residual -> fp32 ----------------
__global__ __launch_bounds__(256) void combine4(
    const unsigned short* __restrict__ part01, const unsigned short* __restrict__ part23,
    const float* __restrict__ res, const float* __restrict__ bias,
    float* __restrict__ out, int MN, int N)
{
  const int idx = (blockIdx.x * 256 + threadIdx.x) * 4;
  if (idx >= MN) return;
  const u16x4 a0 = *(const u16x4*)(part01 + idx);
  const u16x4 a1 = *(const u16x4*)(part01 + MN + idx);
  const u16x4 a2 = *(const u16x4*)(part23 + idx);
  const u16x4 a3 = *(const u16x4*)(part23 + MN + idx);
  const float4 rr = *(const float4*)(res + idx);
  const float4 bb = *(const float4*)(bias + (idx % N));
  float4 o;
  o.x = bits2f(a0[0]) + bits2f(a1[0]) + bits2f(a2[0]) + bits2f(a3[0]) + rr.x + bb.x;
  o.y = bits2f(a0[1]) + bits2f(a1[1]) + bits2f(a2[1]) + bits2f(a3[1]) + rr.y + bb.y;
  o.z = bits2f(a0[2]) + bits2f(a1[2]) + bits2f(a2[2]) + bits2f(a3[2]) + rr.z + bb.z;
  o.w = bits2f(a0[3]) + bits2f(a1[3]) + bits2f(a2[3]) + bits2f(a3[3]) + rr.w + bb.w;
  *(float4*)(out + idx) = o;
}

// ---------------- fused: combine 2 bf16 partials + bias + residual -> hbuf, then LN -> bf16 ----------------
__global__ __launch_bounds__(256) void combine2_ln(
    const unsigned short* __restrict__ part, const float* __restrict__ res,
    const float* __restrict__ bias, const float* __restrict__ gain,
    const float* __restrict__ off, float* __restrict__ hout,
    __hip_bfloat16* __restrict__ lnout)
{
  const int wave = threadIdx.x >> 6;
  const int lane = threadIdx.x & 63;
  const int row = blockIdx.x * 4 + wave;
  const int MN = MM * DD;
  const size_t rbase = (size_t)row * DD;

  float v[3][4];
  float s1 = 0.f, s2 = 0.f;
#pragma unroll
  for (int j = 0; j < 3; ++j) {
    const int c = (j * 64 + lane) * 4;
    const size_t idx = rbase + c;
    const u16x4 a0 = *(const u16x4*)(part + idx);
    const u16x4 a1 = *(const u16x4*)(part + MN + idx);
    const float4 rr = *(const float4*)(res + idx);
    const float4 bb = *(const float4*)(bias + c);
    v[j][0] = bits2f(a0[0]) + bits2f(a1[0]) + rr.x + bb.x;
    v[j][1] = bits2f(a0[1]) + bits2f(a1[1]) + rr.y + bb.y;
    v[j][2] = bits2f(a0[2]) + bits2f(a1[2]) + rr.z + bb.z;
    v[j][3] = bits2f(a0[3]) + bits2f(a1[3]) + rr.w + bb.w;
    float4 hv = { v[j][0], v[j][1], v[j][2], v[j][3] };
    *(float4*)(hout + idx) = hv;
    s1 += v[j][0] + v[j][1] + v[j][2] + v[j][3];
    s2 += v[j][0]*v[j][0] + v[j][1]*v[j][1] + v[j][2]*v[j][2] + v[j][3]*v[j][3];
  }
#pragma unroll
  for (int d = 1; d < 64; d <<= 1) {
    s1 += __shfl_xor(s1, d);
    s2 += __shfl_xor(s2, d);
  }
  const float mean = s1 * (1.0f / 768.0f);
  const float var = fmaxf(s2 * (1.0f / 768.0f) - mean * mean, 0.0f);
  const float rs = 1.0f / (sqrtf(var) + 1e-5f);

  unsigned short* orow = (unsigned short*)lnout + rbase;
#pragma unroll
  for (int j = 0; j < 3; ++j) {
    const int c = (j * 64 + lane) * 4;
    const float4 g4 = *(const float4*)(gain + c);
    const float4 o4 = *(const float4*)(off + c);
    u16x4 pk;
    pk[0] = bf16bits(g4.x * ((v[j][0] - mean) * rs) + o4.x);
    pk[1] = bf16bits(g4.y * ((v[j][1] - mean) * rs) + o4.y);
    pk[2] = bf16bits(g4.z * ((v[j][2] - mean) * rs) + o4.z);
    pk[3] = bf16bits(g4.w * ((v[j][3] - mean) * rs) + o4.w);
    *(u16x4*)(orow + c) = pk;
  }
}

// ---------------- Flash attention: kv-split 4 (register-neutral occupancy boost) ----------------
// 1536 blocks x 256 threads (4 warps = one 32-row q strip, kv-split 4).
// Per-thread register state identical to the r18/r24 kv-split-2 kernel (same
// kf/vf/o0/o1/qf footprint); each warp walks tiles t = c, c+4, ... with K(t+4)
// prefetch. Waves/CU rises 12 -> 16 (LDS 34.3KB -> 4 blocks/CU) and the longest
// per-warp serial chain halves. LSE combine extends to 4 partials.
__global__ __launch_bounds__(256, 3) void attn_kernel(
    const __hip_bfloat16* __restrict__ qkv, const char* __restrict__ kimg,
    const char* __restrict__ vimg, __hip_bfloat16* __restrict__ outp)
{
  const int HD = 3 * DD;   // 2304
  const int id = blockIdx.x;          // 0..1535
  const int xcd = id & 7;
  const int j = id >> 3;              // 0..191 within XCD
  const int s2 = 63 - j / 3;          // strip 0..63, heavy first
  const int bhl = j - 3 * (j / 3);
  const int bh = xcd * 3 + bhl;       // 24 heads = 8 XCD x 3
  const int b = bh / HH, h = bh - (bh / HH) * HH;

  const int q0w = s2 * 32;
  const int tid = threadIdx.x;
  const int c = tid >> 6;             // warp = kv-split index 0..3
  const int lane = tid & 63;
  const int col = lane & 31, hi = lane >> 5;
  const int qg = q0w + col;

  const size_t base = (size_t)b * SS * HD;
  const __hip_bfloat16* Qp = qkv + base + h * DHH;
  const char* kimg_h = kimg + (size_t)bh * 32 * 8192;
  const char* vimg_h = vimg + (size_t)bh * 32 * 8192;

  __shared__ __align__(16) char sm[34304];   // opart [4][32][65] f32 + mlp [4][64] f32

  bf16x8 qf[4];
#pragma unroll
  for (int kc = 0; kc < 4; ++kc)
    qf[kc] = *(const bf16x8*)(Qp + (size_t)qg * HD + kc * 16 + hi * 8);

  f32x16 o0 = {}, o1 = {};
  float mreg = -1e30f, lreg = 0.f;
  const float CS = 0.125f * 1.44269504f;   // (1/sqrt(64)) * log2(e)

  const int ntiles = (q0w >> 6) + 1;

  // prologue: K fragments of this warp's first tile (c < 32 always in-bounds)
  bf16x8 kf[8];
  {
    const char* ks = kimg_h + (size_t)c * 8192 + lane * 16;
#pragma unroll
    for (int f = 0; f < 8; ++f) kf[f] = *(const bf16x8*)(ks + f * 1024);
  }

  for (int t = c; t < ntiles; t += 4) {
    const int kv0 = t * 64;
    // ---- QK^T (swapped): D col = q (lane-local) ----
    f32x16 s0 = {}, s1 = {};
    __builtin_amdgcn_s_setprio(1);
#pragma unroll
    for (int kc = 0; kc < 4; ++kc) {
      s0 = __builtin_amdgcn_mfma_f32_32x32x16_bf16(kf[kc * 2],     qf[kc], s0, 0, 0, 0);
      s1 = __builtin_amdgcn_mfma_f32_32x32x16_bf16(kf[kc * 2 + 1], qf[kc], s1, 0, 0, 0);
    }
    __builtin_amdgcn_s_setprio(0);
    // ---- issue V loads for this tile AND K loads for tile t+4 ----
    bf16x8 vf[8];
    {
      const char* vs = vimg_h + (size_t)t * 8192 + lane * 16;
#pragma unroll
      for (int f = 0; f < 8; ++f) vf[f] = *(const bf16x8*)(vs + f * 1024);
    }
    if (t + 4 < ntiles) {
      const char* ks = kimg_h + (size_t)(t + 4) * 8192 + lane * 16;
#pragma unroll
      for (int f = 0; f < 8; ++f) kf[f] = *(const bf16x8*)(ks + f * 1024);
    }
    // ---- causal mask (diagonal tile only) ----
    if (kv0 + 63 > q0w) {
#pragma unroll
      for (int r = 0; r < 16; ++r) {
        const int tl = (r & 3) + 8 * (r >> 2) + 4 * hi;
        s0[r] = (kv0 + tl <= qg) ? s0[r] : -1e30f;
        s1[r] = (kv0 + 32 + tl <= qg) ? s1[r] : -1e30f;
      }
    }
    // ---- online softmax, fully in-register ----
    float mx = s0[0];
#pragma unroll
    for (int r = 1; r < 16; ++r) mx = fmaxf(mx, s0[r]);
#pragma unroll
    for (int r = 0; r < 16; ++r) mx = fmaxf(mx, s1[r]);
    mx = fmaxf(mx, __shfl_xor(mx, 32));
    const float mnew = fmaxf(mreg, mx);
    const float alpha = exp2f((mreg - mnew) * CS);
    mreg = mnew;
    const float mc = mnew * CS;
    float ps = 0.f;
#pragma unroll
    for (int r = 0; r < 16; ++r) {
      const float p0 = exp2f(s0[r] * CS - mc); s0[r] = p0; ps += p0;
      const float p1 = exp2f(s1[r] * CS - mc); s1[r] = p1; ps += p1;
    }
    ps += __shfl_xor(ps, 32);
    lreg = lreg * alpha + ps;
#pragma unroll
    for (int r = 0; r < 16; ++r) { o0[r] *= alpha; o1[r] *= alpha; }

    // ---- pack P rows to bf16 pairs ----
    u32 pk0[4][2], pk1[4][2];
#pragma unroll
    for (int qd = 0; qd < 4; ++qd) {
      pk0[qd][0] = pack2(s0[4 * qd + 0], s0[4 * qd + 1]);
      pk0[qd][1] = pack2(s0[4 * qd + 2], s0[4 * qd + 3]);
      pk1[qd][0] = pack2(s1[4 * qd + 0], s1[4 * qd + 1]);
      pk1[qd][1] = pack2(s1[4 * qd + 2], s1[4 * qd + 3]);
    }
    // ---- PV: O += mfma(V-frag (A), P-frag (B)) ----
#pragma unroll
    for (int kc = 0; kc < 4; ++kc) {
      const int qa = 2 * (kc & 1), qb = qa + 1;
      const u32 A0 = (kc < 2) ? pk0[qa][0] : pk1[qa][0];
      const u32 A1 = (kc < 2) ? pk0[qa][1] : pk1[qa][1];
      const u32 B0 = (kc < 2) ? pk0[qb][0] : pk1[qb][0];
      const u32 B1 = (kc < 2) ? pk0[qb][1] : pk1[qb][1];
      const u32 send0 = hi ? A0 : B0;
      const u32 send1 = hi ? A1 : B1;
      const u32 recv0 = __shfl_xor(send0, 32);
      const u32 recv1 = __shfl_xor(send1, 32);
      const u32 su0 = hi ? B0 : A0;
      const u32 su1 = hi ? B1 : A1;
      union { u32 u[4]; bf16x8 v; } pf;
      pf.u[0] = hi ? recv0 : su0;
      pf.u[1] = hi ? recv1 : su1;
      pf.u[2] = hi ? su0 : recv0;
      pf.u[3] = hi ? su1 : recv1;
      __builtin_amdgcn_s_setprio(1);
      o0 = __builtin_amdgcn_mfma_f32_32x32x16_bf16(vf[kc * 2],     pf.v, o0, 0, 0, 0);
      o1 = __builtin_amdgcn_mfma_f32_32x32x16_bf16(vf[kc * 2 + 1], pf.v, o1, 0, 0, 0);
      __builtin_amdgcn_s_setprio(0);
    }
  }

  // ---- combine the 4 kv-split partials via LDS (1 barrier) ----
  float* opart = (float*)sm;                 // [4][32][65]
  float* mlp   = (float*)(sm + 33280);       // [c][0][q]=m, [c][1][q]=l
#pragma unroll
  for (int r = 0; r < 16; ++r) {
    const int d = (r & 3) + 8 * (r >> 2) + 4 * hi;
    opart[(c * 32 + col) * 65 + d]      = o0[r];
    opart[(c * 32 + col) * 65 + d + 32] = o1[r];
  }
  if (hi == 0) {
    mlp[c * 64 + col]      = mreg;
    mlp[c * 64 + 32 + col] = lreg;
  }
  __syncthreads();

  const int q = tid >> 3;            // 0..31
  const int d0 = (tid & 7) * 8;      // 0..56
  float mcv[4], lcv[4];
#pragma unroll
  for (int cc = 0; cc < 4; ++cc) {
    mcv[cc] = mlp[cc * 64 + q];
    lcv[cc] = mlp[cc * 64 + 32 + q];
  }
  const float mstar = fmaxf(fmaxf(mcv[0], mcv[1]), fmaxf(mcv[2], mcv[3]));
  float av[4], lstar = 0.f;
#pragma unroll
  for (int cc = 0; cc < 4; ++cc) {
    av[cc] = exp2f((mcv[cc] - mstar) * CS);
    lstar += av[cc] * lcv[cc];
  }
  const float inv = 1.0f / lstar;
  float acc[8] = {};
#pragma unroll
  for (int cc = 0; cc < 4; ++cc) {
    const float a = av[cc];
#pragma unroll
    for (int e = 0; e < 8; ++e)
      acc[e] += a * opart[(cc * 32 + q) * 65 + d0 + e];
  }
  unsigned short* orow = (unsigned short*)outp +
      (size_t)(b * SS + q0w + q) * DD + h * DHH + d0;
  u16x8 w8;
#pragma unroll
  for (int e = 0; e < 8; ++e) w8[e] = bf16bits(acc[e] * inv);
  *(u16x8*)orow = w8;
}

// ---------------- host ----------------
extern "C" void kernel_launch(void* const* d_in, const int* in_sizes, int n_in,
                              void* d_out, int out_size, void* d_ws, size_t ws_size,
                              hipStream_t stream)
{
  (void)in_sizes; (void)n_in; (void)out_size; (void)ws_size;
  const float* X  = (const float*)d_in[0];
  const float* Wq = (const float*)d_in[1];
  const float* bq = (const float*)d_in[2];
  const float* Wk = (const float*)d_in[3];
  const float* bk = (const float*)d_in[4];
  const float* Wv = (const float*)d_in[5];
  const float* bv = (const float*)d_in[6];
  const float* W0 = (const float*)d_in[7];
  const float* b0 = (const float*)d_in[8];
  const float* W1 = (const float*)d_in[9];
  const float* b1 = (const float*)d_in[10];
  const float* W2 = (const float*)d_in[11];
  const float* b2 = (const float*)d_in[12];
  const float* g1 = (const float*)d_in[13];
  const float* o1 = (const float*)d_in[14];
  const float* g2 = (const float*)d_in[15];
  const float* o2 = (const float*)d_in[16];

  char* ws = (char*)d_ws;
  auto alloc = [&](size_t bytes) {
    char* p = ws;
    ws += (bytes + 255) & ~(size_t)255;
    return p;
  };
  __hip_bfloat16* ln1    = (__hip_bfloat16*)alloc((size_t)MM * DD * 2);
  __hip_bfloat16* qkvb16 = (__hip_bfloat16*)alloc((size_t)MM * 3 * DD * 2);
  __hip_bfloat16* attnb  = (__hip_bfloat16*)alloc((size_t)MM * DD * 2);
  float*          hbuf   = (float*)alloc((size_t)MM * DD * 4);
  __hip_bfloat16* ln2    = (__hip_bfloat16*)alloc((size_t)MM * DD * 2);
  __hip_bfloat16* ffn1   = (__hip_bfloat16*)alloc((size_t)MM * DFF * 2);
  __hip_bfloat16* WqkvT  = (__hip_bfloat16*)alloc((size_t)3 * DD * DD * 2);
  __hip_bfloat16* W0T    = (__hip_bfloat16*)alloc((size_t)DD * DD * 2);
  __hip_bfloat16* W1T    = (__hip_bfloat16*)alloc((size_t)DFF * DD * 2);
  __hip_bfloat16* W2T    = (__hip_bfloat16*)alloc((size_t)DD * DFF * 2);
  float*          qkvbias= (float*)alloc((size_t)3 * DD * 4);
  unsigned short* part23 = (unsigned short*)alloc((size_t)2 * MM * DD * 2);  // 2 bf16 planes
  char*           kimg   = alloc((size_t)24 * 32 * 8192);           // K fragment images
  char*           vimg   = alloc((size_t)24 * 32 * 8192);           // V fragment images
  // bf16 FFN2 splits 0,1 alias ln1 (+ spill into qkvb16; both dead by FFN2)
  unsigned short* part01 = (unsigned short*)ln1;

  // fused prolog: qkv-transpose (+bias), W-transposes, LN1 — one launch
  prolog_kernel<<<2752, 256, 0, stream>>>(
      Wq, Wk, Wv, bq, bk, bv, WqkvT, qkvbias,
      W0, W1, W2, W0T, W1T, W2T,
      X, g1, o1, ln1);

  gemm_bt<false, true, false><<<dim3(3 * DD / 128, MM / 128), 256, 0, stream>>>(
      ln1, WqkvT, qkvbias, nullptr, qkvb16, MM, 3 * DD, DD);
  kvimg_kernel<<<dim3(SS / 64, BB * HH), 256, 0, stream>>>(qkvb16, kimg, vimg);
  attn_kernel<<<1536, 256, 0, stream>>>(qkvb16, kimg, vimg, attnb);
  // proj via split-K=2 (bf16 partials in part23's two planes)
  gemm_bt_sk<<<dim3(DD / 128, MM / 128, 2), 256, 0, stream>>>(
      attnb, W0T, part23, part23, MM, DD, DD, DD / 2);
  // fused combine + LN2: hbuf (residual for FFN2) + ln2 (FFN1 input)
  combine2_ln<<<MM / 4, 256, 0, stream>>>(
      part23, X, b0, g2, o2, hbuf, ln2);
  gemm_bt<true, true, false><<<dim3(DFF / 128, MM / 128), 256, 0, stream>>>(
      ln2, W1T, b1, nullptr, ffn1, MM, DFF, DD);
  // FFN2 via split-K=4: bf16 partials then combine(+bias+residual)
  gemm_bt_sk<<<dim3(DD / 128, MM / 128, 4), 256, 0, stream>>>(
      ffn1, W2T, part01, part23, MM, DD, DFF, DFF / 4);
  combine4<<<(MM * DD) / 1024, 256, 0, stream>>>(
      part01, part23, hbuf, b2, (float*)d_out, MM * DD, DD);
}